// Round 1
// baseline (434.477 us; speedup 1.0000x reference)
//
#include <hip/hip_runtime.h>
#include <math.h>

#define LHIST 50
#define DEMB 32
#define LSTR 68   // hist row stride in floats (k-dim padded, 8B-aligned rows)
#define WSTR 68   // Wqt row stride in floats
#define CSTR 20   // MLP LDS row stride (float4-aligned, non-pow2 banks)

// ---------- prep: fold aw1 (256x80) into A = W1+W3 (64x80), Bm = W2-W3 (64x80)
__global__ void prep_kernel(const float* __restrict__ aw1,
                            float* __restrict__ A, float* __restrict__ Bm) {
    int i = blockIdx.x * 256 + threadIdx.x;
    if (i < 64 * 80) {
        float w1 = aw1[i];                 // rows 0..63
        float w2 = aw1[64 * 80 + i];       // rows 64..127
        float w3 = aw1[128 * 80 + i];      // rows 128..191
        A[i]  = w1 + w3;
        Bm[i] = w2 - w3;
    }
}

// ---------- attention: 2 batch rows per 256-thread block ----------
__global__ void __launch_bounds__(256) attn_kernel(
    const int* __restrict__ cid, const int* __restrict__ cg,
    const int* __restrict__ cc,  const int* __restrict__ hg,
    const int* __restrict__ hc,
    const float* __restrict__ user_table, const float* __restrict__ item_table,
    const float* __restrict__ cat_table,
    const float* __restrict__ aw1, const float* __restrict__ ab1,
    const float* __restrict__ aw2, const float* __restrict__ ab2,
    const float* __restrict__ Aw, const float* __restrict__ Bw,
    float* __restrict__ combined)
{
    __shared__ float sh_hist[2][LHIST][LSTR];
    __shared__ float sh_wq[2][80][WSTR];     // transposed: [j][k]
    __shared__ float sh_q[2][64];
    __shared__ float sh_bias[2][80];
    __shared__ float sh_sc[2][64];
    __shared__ float sh_wt[2][64];
    __shared__ float sh_aw2[80];

    const int t = threadIdx.x;
    const int b0 = blockIdx.x * 2;

    // ---- phase 1: load q (cand embeddings) + hist rows + aw2 ----
    if (t < 128) {
        int qbi = t >> 6, k = t & 63;
        int b = b0 + qbi;
        float v;
        if (k < 32) v = item_table[(size_t)cg[b] * 32 + k];
        else        v = cat_table[(size_t)cc[b] * 32 + (k - 32)];
        sh_q[qbi][k] = v;
    }
    if (t < 80) sh_aw2[t] = aw2[t];
    // 2 b * 100 gather-rows * 8 float4 segments = 1600 slots
    for (int i = t; i < 1600; i += 256) {
        int gbi = i / 800;
        int rem = i - gbi * 800;
        int row = rem >> 3;          // 0..99
        int seg = rem & 7;           // float4 segment
        int b = b0 + gbi;
        int l = (row < LHIST) ? row : row - LHIST;
        int isCat = (row >= LHIST);
        int idx = isCat ? hc[b * LHIST + l] : hg[b * LHIST + l];
        const float* src = (isCat ? cat_table : item_table) + (size_t)idx * 32 + seg * 4;
        float4 v = *(const float4*)src;
        *(float4*)&sh_hist[gbi][l][(isCat ? 32 : 0) + seg * 4] = v;
    }
    __syncthreads();

    // ---- phase 2: build Wqt[j][k] = Bm[k][j] + q[k]*W4[k][j]; bias[j] = ab1[j] + q.A[:,j]
    {
        const float* W4 = aw1 + 192 * 80;
        int pbi = t >> 7;
        int tt = t & 127;
        for (int i = tt; i < 5120; i += 128) {
            int k = i / 80;
            int j = i - k * 80;
            float w = Bw[i] + sh_q[pbi][k] * W4[i];
            sh_wq[pbi][j][k] = w;
        }
        if (tt < 80) {
            float s = ab1[tt];
            #pragma unroll 8
            for (int k = 0; k < 64; ++k) s += sh_q[pbi][k] * Aw[k * 80 + tt];
            sh_bias[pbi][tt] = s;
        }
    }
    __syncthreads();

    // ---- phase 3: u[l][j] = bias[j] + h_l . Wq[:,j];  7l x 5j tile per thread
    const int bi = t >> 7;          // 128 threads per batch row
    const int lg = (t >> 4) & 7;    // 8 l-groups
    const int jl = t & 15;          // 16 j-lanes
    float acc[7][5];
    float a2[5];
    #pragma unroll
    for (int r = 0; r < 5; ++r) {
        float bs = sh_bias[bi][jl + 16 * r];
        a2[r] = sh_aw2[jl + 16 * r];
        #pragma unroll
        for (int s = 0; s < 7; ++s) acc[s][r] = bs;
    }
    int lrow[7];
    #pragma unroll
    for (int s = 0; s < 7; ++s) { int l = lg + 8 * s; lrow[s] = (l < LHIST) ? l : 0; }

    for (int k = 0; k < 64; k += 2) {
        float2 h[7];
        #pragma unroll
        for (int s = 0; s < 7; ++s) h[s] = *(const float2*)&sh_hist[bi][lrow[s]][k];
        #pragma unroll
        for (int r = 0; r < 5; ++r) {
            float2 w = *(const float2*)&sh_wq[bi][jl + 16 * r][k];
            #pragma unroll
            for (int s = 0; s < 7; ++s)
                acc[s][r] += h[s].x * w.x + h[s].y * w.y;
        }
    }

    // relu + dot with aw2 -> per-l score partials; reduce over 16 j-lanes
    #pragma unroll
    for (int s = 0; s < 7; ++s) {
        float p = 0.f;
        #pragma unroll
        for (int r = 0; r < 5; ++r) {
            float u = acc[s][r];
            p += (u > 0.f ? u : 0.f) * a2[r];
        }
        p += __shfl_xor(p, 1);
        p += __shfl_xor(p, 2);
        p += __shfl_xor(p, 4);
        p += __shfl_xor(p, 8);
        if (jl == 0) {
            int l = lg + 8 * s;
            if (l < LHIST) sh_sc[bi][l] = p + ab2[0];
        }
    }
    __syncthreads();

    // ---- phase 4: masked softmax, one wave per batch row (waves 0 and 2) ----
    {
        int w = t >> 6;
        if ((w & 1) == 0) {
            int sbi = w >> 1;
            int lane = t & 63;
            int b = b0 + sbi;
            float sc = -INFINITY;
            if (lane < LHIST) {
                sc = sh_sc[sbi][lane];
                if (hg[b * LHIST + lane] == 0) sc = -1e9f;
            }
            float m = sc;
            #pragma unroll
            for (int off = 32; off > 0; off >>= 1) m = fmaxf(m, __shfl_xor(m, off));
            float e = (lane < LHIST) ? __expf(sc - m) : 0.f;
            float ssum = e;
            #pragma unroll
            for (int off = 32; off > 0; off >>= 1) ssum += __shfl_xor(ssum, off);
            if (lane < LHIST) sh_wt[sbi][lane] = e / ssum;
        }
    }
    __syncthreads();

    // ---- phase 5: att = sum_l w[l]*hist[l][:], write combined row ----
    {
        int w = t >> 6;
        if ((w & 1) == 0) {
            int sbi = w >> 1;
            int lane = t & 63;   // d
            int b = b0 + sbi;
            float att = 0.f;
            for (int l = 0; l < LHIST; ++l)
                att += sh_wt[sbi][l] * sh_hist[sbi][l][lane];
            float* crow = combined + (size_t)b * 160;
            crow[32 + lane] = sh_q[sbi][lane];
            crow[96 + lane] = att;
            if (lane < 32) crow[lane] = user_table[(size_t)cid[b] * 32 + lane];
        }
    }
}

// ---------- MLP: 16 batch rows per 256-thread block ----------
__global__ void __launch_bounds__(256) mlp_kernel(
    const float* __restrict__ combined,
    const float* __restrict__ mw1, const float* __restrict__ mb1,
    const float* __restrict__ mw2, const float* __restrict__ mb2,
    const float* __restrict__ mw3, const float* __restrict__ mb3,
    float* __restrict__ out)
{
    __shared__ float cbuf[160][CSTR];
    __shared__ float z1t[256][CSTR];
    __shared__ float z2t[128][CSTR];
    const int t = threadIdx.x;
    const int b0 = blockIdx.x * 16;

    for (int i = t; i < 16 * 160; i += 256) {
        int bi = i / 160;
        int k = i - bi * 160;
        cbuf[k][bi] = combined[(size_t)(b0 + bi) * 160 + k];
    }
    __syncthreads();

    // z1[b][j] for j = t, all 16 b
    {
        float acc[16];
        float bj = mb1[t];
        #pragma unroll
        for (int b = 0; b < 16; ++b) acc[b] = bj;
        for (int k = 0; k < 160; ++k) {
            float w = mw1[k * 256 + t];
            float4 c0 = *(const float4*)&cbuf[k][0];
            float4 c1 = *(const float4*)&cbuf[k][4];
            float4 c2 = *(const float4*)&cbuf[k][8];
            float4 c3 = *(const float4*)&cbuf[k][12];
            acc[0]  += w * c0.x; acc[1]  += w * c0.y; acc[2]  += w * c0.z; acc[3]  += w * c0.w;
            acc[4]  += w * c1.x; acc[5]  += w * c1.y; acc[6]  += w * c1.z; acc[7]  += w * c1.w;
            acc[8]  += w * c2.x; acc[9]  += w * c2.y; acc[10] += w * c2.z; acc[11] += w * c2.w;
            acc[12] += w * c3.x; acc[13] += w * c3.y; acc[14] += w * c3.z; acc[15] += w * c3.w;
        }
        #pragma unroll
        for (int b = 0; b < 16; ++b) acc[b] = fmaxf(acc[b], 0.f);
        *(float4*)&z1t[t][0]  = make_float4(acc[0],  acc[1],  acc[2],  acc[3]);
        *(float4*)&z1t[t][4]  = make_float4(acc[4],  acc[5],  acc[6],  acc[7]);
        *(float4*)&z1t[t][8]  = make_float4(acc[8],  acc[9],  acc[10], acc[11]);
        *(float4*)&z1t[t][12] = make_float4(acc[12], acc[13], acc[14], acc[15]);
    }
    __syncthreads();

    // z2[b][j] for j = t&127, 8 b per half
    {
        int j2 = t & 127, half = t >> 7;
        float acc[8];
        float bj = mb2[j2];
        #pragma unroll
        for (int b = 0; b < 8; ++b) acc[b] = bj;
        for (int k = 0; k < 256; ++k) {
            float w = mw2[k * 128 + j2];
            float4 c0 = *(const float4*)&z1t[k][half * 8];
            float4 c1 = *(const float4*)&z1t[k][half * 8 + 4];
            acc[0] += w * c0.x; acc[1] += w * c0.y; acc[2] += w * c0.z; acc[3] += w * c0.w;
            acc[4] += w * c1.x; acc[5] += w * c1.y; acc[6] += w * c1.z; acc[7] += w * c1.w;
        }
        #pragma unroll
        for (int b = 0; b < 8; ++b) acc[b] = fmaxf(acc[b], 0.f);
        *(float4*)&z2t[j2][half * 8]     = make_float4(acc[0], acc[1], acc[2], acc[3]);
        *(float4*)&z2t[j2][half * 8 + 4] = make_float4(acc[4], acc[5], acc[6], acc[7]);
    }
    __syncthreads();

    // out[b] = z2[b] . mw3 + mb3
    {
        int bi = t >> 4, kl = t & 15;
        float p = 0.f;
        #pragma unroll 4
        for (int k = kl; k < 128; k += 16) p += z2t[k][bi] * mw3[k];
        p += __shfl_xor(p, 1);
        p += __shfl_xor(p, 2);
        p += __shfl_xor(p, 4);
        p += __shfl_xor(p, 8);
        if (kl == 0) out[b0 + bi] = p + mb3[0];
    }
}

extern "C" void kernel_launch(void* const* d_in, const int* in_sizes, int n_in,
                              void* d_out, int out_size, void* d_ws, size_t ws_size,
                              hipStream_t stream) {
    const int*   cid = (const int*)d_in[0];
    const int*   cg  = (const int*)d_in[1];
    const int*   cc  = (const int*)d_in[2];
    const int*   hg  = (const int*)d_in[3];
    const int*   hc  = (const int*)d_in[4];
    const float* user_table = (const float*)d_in[5];
    const float* item_table = (const float*)d_in[6];
    const float* cat_table  = (const float*)d_in[7];
    const float* aw1 = (const float*)d_in[8];
    const float* ab1 = (const float*)d_in[9];
    const float* aw2 = (const float*)d_in[10];
    const float* ab2 = (const float*)d_in[11];
    const float* mw1 = (const float*)d_in[12];
    const float* mb1 = (const float*)d_in[13];
    const float* mw2 = (const float*)d_in[14];
    const float* mb2 = (const float*)d_in[15];
    const float* mw3 = (const float*)d_in[16];
    const float* mb3 = (const float*)d_in[17];
    float* out = (float*)d_out;

    const int B = in_sizes[0];           // 16384
    float* ws = (float*)d_ws;
    float* Aw = ws;                      // 64*80
    float* Bw = ws + 5120;               // 64*80
    float* combined = ws + 10240;        // B*160

    prep_kernel<<<20, 256, 0, stream>>>(aw1, Aw, Bw);
    attn_kernel<<<B / 2, 256, 0, stream>>>(cid, cg, cc, hg, hc,
                                           user_table, item_table, cat_table,
                                           aw1, ab1, aw2, ab2, Aw, Bw, combined);
    mlp_kernel<<<B / 16, 256, 0, stream>>>(combined, mw1, mb1, mw2, mb2, mw3, mb3, out);
}

// Round 2
// 353.242 us; speedup vs baseline: 1.2300x; 1.2300x over previous
//
#include <hip/hip_runtime.h>
#include <math.h>

#define LHIST 50
#define ASTR 136   // bf16 row stride for A/B LDS tiles (272B = 17*16B, bank-friendly)

typedef __attribute__((ext_vector_type(8))) short bf16x8;
typedef __attribute__((ext_vector_type(4))) float f32x4;

__device__ __forceinline__ unsigned short f2bf(float f) {
    union { float f; unsigned u; } v; v.f = f;
    unsigned r = v.u + 0x7fff + ((v.u >> 16) & 1);   // RNE
    return (unsigned short)(r >> 16);
}
__device__ __forceinline__ float bf2f(unsigned short h) {
    union { unsigned u; float f; } v; v.u = ((unsigned)h) << 16;
    return v.f;
}

// ---------- prep: Aw = W1+W3 (fp32 [k=64][j=80]); Wcat bf16 [n=80][k=128] = [Bm^T | W4^T]
__global__ void prep_kernel(const float* __restrict__ aw1,
                            float* __restrict__ Aw, unsigned short* __restrict__ Wcat) {
    int i = blockIdx.x * 256 + threadIdx.x;
    if (i < 64 * 80) {
        Aw[i] = aw1[i] + aw1[128 * 80 + i];          // W1 + W3
    }
    if (i < 80 * 128) {
        int n = i >> 7, k = i & 127;
        float v;
        if (k < 64) v = aw1[(64 + k) * 80 + n] - aw1[(128 + k) * 80 + n];  // Bm = W2-W3
        else        v = aw1[(192 + (k - 64)) * 80 + n];                    // W4
        Wcat[i] = f2bf(v);
    }
}

// ---------- attention: 2 batch rows / 256-thread block, MFMA bf16 ----------
__global__ void __launch_bounds__(256) attn_kernel(
    const int* __restrict__ cid, const int* __restrict__ cg,
    const int* __restrict__ cc,  const int* __restrict__ hg,
    const int* __restrict__ hc,
    const float* __restrict__ user_table, const float* __restrict__ item_table,
    const float* __restrict__ cat_table,
    const float* __restrict__ ab1, const float* __restrict__ aw2,
    const float* __restrict__ Aw, const unsigned short* __restrict__ Wcat,
    float* __restrict__ combined)
{
    __shared__ __align__(16) unsigned short sh_A[128 * ASTR];  // rows = b*64+l, k=0..127 (h | h*q)
    __shared__ __align__(16) unsigned short sh_B[80 * ASTR];   // [n][k]
    __shared__ __align__(16) float sh_q[2][64];
    __shared__ float sh_bias[2][80];
    __shared__ float sh_sc[2][64];
    __shared__ float sh_aw2[80];

    const int t = threadIdx.x;
    const int b0 = blockIdx.x * 2;

    // ---- phase 0: weights -> LDS, q -> LDS, aw2 -> LDS ----
    for (int i = t; i < 80 * 16; i += 256) {          // 80 rows x 16 segs of 8 bf16
        int n = i >> 4, s = i & 15;
        uint4 w = *(const uint4*)&Wcat[n * 128 + s * 8];
        *(uint4*)&sh_B[n * ASTR + s * 8] = w;
    }
    if (t < 128) {
        int qbi = t >> 6, k = t & 63;
        int b = b0 + qbi;
        float v = (k < 32) ? item_table[(size_t)cg[b] * 32 + k]
                           : cat_table[(size_t)cc[b] * 32 + (k - 32)];
        sh_q[qbi][k] = v;
    }
    if (t < 80) sh_aw2[t] = aw2[t];
    __syncthreads();

    // ---- phase 1: gather hist -> bf16 LDS rows [h | h*q] ----
    for (int i = t; i < 1600; i += 256) {
        int gbi = i >= 800;
        int rem = i - gbi * 800;
        int l = rem >> 4;            // 0..49
        int seg = rem & 15;          // 0..15
        int isCat = seg >> 3;
        int s = seg & 7;
        int b = b0 + gbi;
        int idx = (isCat ? hc : hg)[b * LHIST + l];
        const float* src = (isCat ? cat_table : item_table) + (size_t)idx * 32 + s * 4;
        float4 v = *(const float4*)src;
        int koff = isCat * 32 + s * 4;
        int row = gbi * 64 + l;
        ushort4 hb; hb.x = f2bf(v.x); hb.y = f2bf(v.y); hb.z = f2bf(v.z); hb.w = f2bf(v.w);
        *(ushort4*)&sh_A[row * ASTR + koff] = hb;
        float4 qv = *(const float4*)&sh_q[gbi][koff];
        ushort4 hq; hq.x = f2bf(v.x * qv.x); hq.y = f2bf(v.y * qv.y);
        hq.z = f2bf(v.z * qv.z); hq.w = f2bf(v.w * qv.w);
        *(ushort4*)&sh_A[row * ASTR + 64 + koff] = hq;
    }
    // bias[b][j] = ab1[j] + q . (W1+W3)[:,j]   (fp32 exact)
    if (t < 160) {
        int bi = t / 80, j = t - bi * 80;
        float s = ab1[j];
        #pragma unroll 8
        for (int k = 0; k < 64; ++k) s += sh_q[bi][k] * Aw[k * 80 + j];
        sh_bias[bi][j] = s;
    }
    __syncthreads();

    // ---- phase 2: MFMA  u[rows=128][j=80] = A[128x128] @ B[128x80] ----
    const int wv = t >> 6;
    const int lane = t & 63;
    const int quad = lane >> 4;
    const int col = lane & 15;

    f32x4 acc[2][5];
    #pragma unroll
    for (int mi = 0; mi < 2; ++mi)
        #pragma unroll
        for (int nt = 0; nt < 5; ++nt)
            acc[mi][nt] = (f32x4){0.f, 0.f, 0.f, 0.f};

    #pragma unroll
    for (int ks = 0; ks < 4; ++ks) {
        int kof = ks * 32 + quad * 8;
        bf16x8 a0 = *(const bf16x8*)&sh_A[((2 * wv) * 16 + col) * ASTR + kof];
        bf16x8 a1 = *(const bf16x8*)&sh_A[((2 * wv + 1) * 16 + col) * ASTR + kof];
        #pragma unroll
        for (int nt = 0; nt < 5; ++nt) {
            bf16x8 bfr = *(const bf16x8*)&sh_B[(nt * 16 + col) * ASTR + kof];
            acc[0][nt] = __builtin_amdgcn_mfma_f32_16x16x32_bf16(a0, bfr, acc[0][nt], 0, 0, 0);
            acc[1][nt] = __builtin_amdgcn_mfma_f32_16x16x32_bf16(a1, bfr, acc[1][nt], 0, 0, 0);
        }
    }

    // ---- phase 3: scores = relu(u + bias) . aw2, reduce over 16 j-lanes ----
    #pragma unroll
    for (int mi = 0; mi < 2; ++mi) {
        int mt = 2 * wv + mi;
        int bl = mt >> 2;                    // batch-local (0/1)
        int lbase = (mt & 3) * 16 + quad * 4;
        float bias_v[5], a2_v[5];
        #pragma unroll
        for (int nt = 0; nt < 5; ++nt) {
            bias_v[nt] = sh_bias[bl][nt * 16 + col];
            a2_v[nt]   = sh_aw2[nt * 16 + col];
        }
        #pragma unroll
        for (int i = 0; i < 4; ++i) {
            float p = 0.f;
            #pragma unroll
            for (int nt = 0; nt < 5; ++nt) {
                float u = acc[mi][nt][i] + bias_v[nt];
                p += fmaxf(u, 0.f) * a2_v[nt];
            }
            p += __shfl_xor(p, 1);
            p += __shfl_xor(p, 2);
            p += __shfl_xor(p, 4);
            p += __shfl_xor(p, 8);
            if (col == 0) sh_sc[bl][lbase + i] = p;
        }
    }
    __syncthreads();

    // ---- phase 4: masked softmax + att + write combined (wave 0 -> b0, wave 1 -> b1) ----
    if (wv < 2) {
        int b = b0 + wv;
        float sc = -INFINITY;
        if (lane < LHIST) {
            sc = sh_sc[wv][lane];
            if (hg[b * LHIST + lane] == 0) sc = -1e9f;
        }
        float m = sc;
        #pragma unroll
        for (int off = 32; off > 0; off >>= 1) m = fmaxf(m, __shfl_xor(m, off));
        float e = (lane < LHIST) ? __expf(sc - m) : 0.f;
        float ssum = e;
        #pragma unroll
        for (int off = 32; off > 0; off >>= 1) ssum += __shfl_xor(ssum, off);
        float w = e / ssum;

        float att = 0.f;
        #pragma unroll 5
        for (int l = 0; l < LHIST; ++l) {
            float wl = __shfl(w, l);
            att += wl * bf2f(sh_A[(wv * 64 + l) * ASTR + lane]);
        }
        float* crow = combined + (size_t)b * 160;
        crow[32 + lane] = sh_q[wv][lane];
        crow[96 + lane] = att;
        if (lane < 32) crow[lane] = user_table[(size_t)cid[b] * 32 + lane];
    }
}

// ---------- MLP: 16 batch rows per 256-thread block ----------
#define CSTR 20
__global__ void __launch_bounds__(256) mlp_kernel(
    const float* __restrict__ combined,
    const float* __restrict__ mw1, const float* __restrict__ mb1,
    const float* __restrict__ mw2, const float* __restrict__ mb2,
    const float* __restrict__ mw3, const float* __restrict__ mb3,
    float* __restrict__ out)
{
    __shared__ float cbuf[160][CSTR];
    __shared__ float z1t[256][CSTR];
    __shared__ float z2t[128][CSTR];
    const int t = threadIdx.x;
    const int b0 = blockIdx.x * 16;

    for (int i = t; i < 16 * 160; i += 256) {
        int bi = i / 160;
        int k = i - bi * 160;
        cbuf[k][bi] = combined[(size_t)(b0 + bi) * 160 + k];
    }
    __syncthreads();

    {
        float acc[16];
        float bj = mb1[t];
        #pragma unroll
        for (int b = 0; b < 16; ++b) acc[b] = bj;
        for (int k = 0; k < 160; ++k) {
            float w = mw1[k * 256 + t];
            float4 c0 = *(const float4*)&cbuf[k][0];
            float4 c1 = *(const float4*)&cbuf[k][4];
            float4 c2 = *(const float4*)&cbuf[k][8];
            float4 c3 = *(const float4*)&cbuf[k][12];
            acc[0]  += w * c0.x; acc[1]  += w * c0.y; acc[2]  += w * c0.z; acc[3]  += w * c0.w;
            acc[4]  += w * c1.x; acc[5]  += w * c1.y; acc[6]  += w * c1.z; acc[7]  += w * c1.w;
            acc[8]  += w * c2.x; acc[9]  += w * c2.y; acc[10] += w * c2.z; acc[11] += w * c2.w;
            acc[12] += w * c3.x; acc[13] += w * c3.y; acc[14] += w * c3.z; acc[15] += w * c3.w;
        }
        #pragma unroll
        for (int b = 0; b < 16; ++b) acc[b] = fmaxf(acc[b], 0.f);
        *(float4*)&z1t[t][0]  = make_float4(acc[0],  acc[1],  acc[2],  acc[3]);
        *(float4*)&z1t[t][4]  = make_float4(acc[4],  acc[5],  acc[6],  acc[7]);
        *(float4*)&z1t[t][8]  = make_float4(acc[8],  acc[9],  acc[10], acc[11]);
        *(float4*)&z1t[t][12] = make_float4(acc[12], acc[13], acc[14], acc[15]);
    }
    __syncthreads();

    {
        int j2 = t & 127, half = t >> 7;
        float acc[8];
        float bj = mb2[j2];
        #pragma unroll
        for (int b = 0; b < 8; ++b) acc[b] = bj;
        for (int k = 0; k < 256; ++k) {
            float w = mw2[k * 128 + j2];
            float4 c0 = *(const float4*)&z1t[k][half * 8];
            float4 c1 = *(const float4*)&z1t[k][half * 8 + 4];
            acc[0] += w * c0.x; acc[1] += w * c0.y; acc[2] += w * c0.z; acc[3] += w * c0.w;
            acc[4] += w * c1.x; acc[5] += w * c1.y; acc[6] += w * c1.z; acc[7] += w * c1.w;
        }
        #pragma unroll
        for (int b = 0; b < 8; ++b) acc[b] = fmaxf(acc[b], 0.f);
        *(float4*)&z2t[j2][half * 8]     = make_float4(acc[0], acc[1], acc[2], acc[3]);
        *(float4*)&z2t[j2][half * 8 + 4] = make_float4(acc[4], acc[5], acc[6], acc[7]);
    }
    __syncthreads();

    {
        int bi = t >> 4, kl = t & 15;
        float p = 0.f;
        #pragma unroll 4
        for (int k = kl; k < 128; k += 16) p += z2t[k][bi] * mw3[k];
        p += __shfl_xor(p, 1);
        p += __shfl_xor(p, 2);
        p += __shfl_xor(p, 4);
        p += __shfl_xor(p, 8);
        if (kl == 0) out[b0 + bi] = p + mb3[0];
    }
}

extern "C" void kernel_launch(void* const* d_in, const int* in_sizes, int n_in,
                              void* d_out, int out_size, void* d_ws, size_t ws_size,
                              hipStream_t stream) {
    const int*   cid = (const int*)d_in[0];
    const int*   cg  = (const int*)d_in[1];
    const int*   cc  = (const int*)d_in[2];
    const int*   hg  = (const int*)d_in[3];
    const int*   hc  = (const int*)d_in[4];
    const float* user_table = (const float*)d_in[5];
    const float* item_table = (const float*)d_in[6];
    const float* cat_table  = (const float*)d_in[7];
    const float* aw1 = (const float*)d_in[8];
    const float* ab1 = (const float*)d_in[9];
    const float* aw2 = (const float*)d_in[10];
    const float* mw1 = (const float*)d_in[12];
    const float* mb1 = (const float*)d_in[13];
    const float* mw2 = (const float*)d_in[14];
    const float* mb2 = (const float*)d_in[15];
    const float* mw3 = (const float*)d_in[16];
    const float* mb3 = (const float*)d_in[17];
    float* out = (float*)d_out;

    const int B = in_sizes[0];                    // 16384
    float* ws = (float*)d_ws;
    float* Aw = ws;                               // 64*80 fp32
    unsigned short* Wcat = (unsigned short*)(ws + 5120);  // 80*128 bf16 (= 5120 floats)
    float* combined = ws + 10240;                 // B*160 fp32

    prep_kernel<<<40, 256, 0, stream>>>(aw1, Aw, Wcat);
    attn_kernel<<<B / 2, 256, 0, stream>>>(cid, cg, cc, hg, hc,
                                           user_table, item_table, cat_table,
                                           ab1, aw2, Aw, Wcat, combined);
    mlp_kernel<<<B / 16, 256, 0, stream>>>(combined, mw1, mb1, mw2, mb2, mw3, mb3, out);
}

// Round 3
// 250.339 us; speedup vs baseline: 1.7356x; 1.4111x over previous
//
#include <hip/hip_runtime.h>
#include <math.h>

#define LHIST 50

typedef __attribute__((ext_vector_type(8))) short bf16x8;
typedef __attribute__((ext_vector_type(4))) float f32x4;

__device__ __forceinline__ unsigned short f2bf(float f) {
    union { float f; unsigned u; } v; v.f = f;
    unsigned r = v.u + 0x7fff + ((v.u >> 16) & 1);   // RNE
    return (unsigned short)(r >> 16);
}
__device__ __forceinline__ float bf2f(unsigned short h) {
    union { unsigned u; float f; } v; v.u = ((unsigned)h) << 16;
    return v.f;
}

// ws float offsets:
//  Awt   [80][64] fp32                          @ 0       (5120)
//  Bmf   frag fp32 [nt5][ks2][lane][8]          @ 5120    (5120)
//  W4f   frag fp32 [nt5][ks2][lane][8]          @ 10240   (5120)
//  W1f   frag bf16 [nt16][ks5][lane][8]         @ 15360   (40960 bf16 = 20480 f)
//  W2f   frag bf16 [nt8][ks8][lane][8]          @ 35840   (32768 bf16 = 16384 f)
//  combined [B][160] fp32                       @ 52224

__global__ void prep_kernel(const float* __restrict__ aw1,
                            const float* __restrict__ mw1,
                            const float* __restrict__ mw2,
                            float* __restrict__ Awt, float* __restrict__ Bmf,
                            float* __restrict__ W4f,
                            unsigned short* __restrict__ W1f,
                            unsigned short* __restrict__ W2f) {
    int i = blockIdx.x * 256 + threadIdx.x;
    if (i < 5120) {
        int j = i >> 6, k = i & 63;
        Awt[i] = aw1[k * 80 + j] + aw1[(128 + k) * 80 + j];     // (W1+W3)^T
        int off = i & 7, lane = (i >> 3) & 63, ks = (i >> 9) & 1, nt = i >> 10;
        int n = nt * 16 + (lane & 15);
        int kk = ks * 32 + (lane >> 4) * 8 + off;
        Bmf[i] = aw1[(64 + kk) * 80 + n] - aw1[(128 + kk) * 80 + n];  // W2-W3
        W4f[i] = aw1[(192 + kk) * 80 + n];
    }
    if (i < 40960) {
        int off = i & 7, lane = (i >> 3) & 63;
        int rest = i >> 9; int ks = rest % 5, nt = rest / 5;
        int n = nt * 16 + (lane & 15);
        int kk = ks * 32 + (lane >> 4) * 8 + off;
        W1f[i] = f2bf(mw1[kk * 256 + n]);
    }
    if (i < 32768) {
        int off = i & 7, lane = (i >> 3) & 63;
        int rest = i >> 9; int ks = rest & 7, nt = rest >> 3;
        int n = nt * 16 + (lane & 15);
        int kk = ks * 32 + (lane >> 4) * 8 + off;
        W2f[i] = f2bf(mw2[kk * 128 + n]);
    }
}

// ---------- attention: 2 batch rows / 256-thread block ----------
__global__ void __launch_bounds__(256, 4) attn_kernel(
    const int* __restrict__ cid, const int* __restrict__ cg,
    const int* __restrict__ cc,  const int* __restrict__ hg,
    const int* __restrict__ hc,
    const float* __restrict__ user_table, const float* __restrict__ item_table,
    const float* __restrict__ cat_table,
    const float* __restrict__ ab1, const float* __restrict__ aw2,
    const float* __restrict__ Awt, const float* __restrict__ Bmf,
    const float* __restrict__ W4f, float* __restrict__ combined)
{
    __shared__ __align__(16) unsigned short sh_A[8192];        // [mt8][ks2][lane][8] (h bf16)
    __shared__ __align__(16) unsigned short sh_Bq[2][5120];    // [b][nt5][ks2][lane][8]
    __shared__ __align__(16) float sh_q[2][64];
    __shared__ float sh_bias[2][80];
    __shared__ float sh_sc[2][64];
    __shared__ float sh_aw2[80];

    const int t = threadIdx.x;
    const int b0 = blockIdx.x * 2;

    // ---- phase 0: q, aw2 ----
    if (t < 128) {
        int qbi = t >> 6, k = t & 63;
        int b = b0 + qbi;
        float v = (k < 32) ? item_table[(size_t)cg[b] * 32 + k]
                           : cat_table[(size_t)cc[b] * 32 + (k - 32)];
        sh_q[qbi][k] = v;
    }
    if (t < 80) sh_aw2[t] = aw2[t];
    __syncthreads();

    // ---- phase 1a: gather hist -> bf16 A frags ----
    for (int i = t; i < 1600; i += 256) {
        int gbi = i >= 800;
        int rem = i - gbi * 800;
        int l = rem >> 4;
        int seg = rem & 15;
        int isCat = seg >> 3;
        int s = seg & 7;
        int b = b0 + gbi;
        int idx = (isCat ? hc : hg)[b * LHIST + l];
        const float* src = (isCat ? cat_table : item_table) + (size_t)idx * 32 + s * 4;
        float4 v = *(const float4*)src;
        int k0 = isCat * 32 + s * 4;
        int m = gbi * 64 + l;
        int mt = m >> 4, colm = m & 15;
        int ks = k0 >> 5, qd = (k0 >> 3) & 3, off = k0 & 7;
        ushort4 hb; hb.x = f2bf(v.x); hb.y = f2bf(v.y); hb.z = f2bf(v.z); hb.w = f2bf(v.w);
        *(ushort4*)&sh_A[(((mt * 2 + ks) * 64 + qd * 16 + colm) << 3) + off] = hb;
    }
    // ---- phase 1b: B' = Bm + diag(q).W4, bf16 frag-packed ----
    for (int i2 = t; i2 < 2560; i2 += 256) {
        int i = i2 * 4;
        int b = i >= 5120;
        int j = i - b * 5120;
        int off = j & 7, lane = (j >> 3) & 63, ks = (j >> 9) & 1;
        int kk = ks * 32 + (lane >> 4) * 8 + off;
        float4 bm = *(const float4*)&Bmf[j];
        float4 w4 = *(const float4*)&W4f[j];
        float4 qv = *(const float4*)&sh_q[b][kk];
        ushort4 r;
        r.x = f2bf(bm.x + qv.x * w4.x);
        r.y = f2bf(bm.y + qv.y * w4.y);
        r.z = f2bf(bm.z + qv.z * w4.z);
        r.w = f2bf(bm.w + qv.w * w4.w);
        *(ushort4*)&sh_Bq[b][j] = r;
    }
    // ---- phase 1c: bias[b][j] = ab1[j] + q.(W1+W3)[:,j] ----
    if (t < 160) {
        int bi = t >= 80;
        int j = t - bi * 80;
        float s = ab1[j];
        const float4* aw = (const float4*)&Awt[j * 64];
        #pragma unroll
        for (int k4 = 0; k4 < 16; ++k4) {
            float4 a = aw[k4];
            float4 q = *(const float4*)&sh_q[bi][k4 * 4];
            s += a.x * q.x + a.y * q.y + a.z * q.z + a.w * q.w;
        }
        sh_bias[bi][j] = s;
    }
    __syncthreads();

    // ---- phase 2: MFMA u[128][80] = A[128x64] @ B'[64x80] ----
    const int wv = t >> 6;
    const int lane = t & 63;
    const int quad = lane >> 4;
    const int col = lane & 15;
    const int bb = wv >> 1;

    f32x4 acc[2][5];
    #pragma unroll
    for (int mi = 0; mi < 2; ++mi)
        #pragma unroll
        for (int nt = 0; nt < 5; ++nt)
            acc[mi][nt] = (f32x4){0.f, 0.f, 0.f, 0.f};

    #pragma unroll
    for (int ks = 0; ks < 2; ++ks) {
        bf16x8 a0 = *(const bf16x8*)&sh_A[(((2 * wv) * 2 + ks) * 64 + lane) * 8];
        bf16x8 a1 = *(const bf16x8*)&sh_A[(((2 * wv + 1) * 2 + ks) * 64 + lane) * 8];
        #pragma unroll
        for (int nt = 0; nt < 5; ++nt) {
            bf16x8 bfr = *(const bf16x8*)&sh_Bq[bb][((nt * 2 + ks) * 64 + lane) * 8];
            acc[0][nt] = __builtin_amdgcn_mfma_f32_16x16x32_bf16(a0, bfr, acc[0][nt], 0, 0, 0);
            acc[1][nt] = __builtin_amdgcn_mfma_f32_16x16x32_bf16(a1, bfr, acc[1][nt], 0, 0, 0);
        }
    }

    // ---- phase 3: scores = relu(u+bias).aw2, reduce over 16 col lanes ----
    #pragma unroll
    for (int mi = 0; mi < 2; ++mi) {
        int mt = 2 * wv + mi;
        int bl = mt >> 2;
        int lbase = (mt & 3) * 16 + quad * 4;
        float bias_v[5], a2_v[5];
        #pragma unroll
        for (int nt = 0; nt < 5; ++nt) {
            bias_v[nt] = sh_bias[bl][nt * 16 + col];
            a2_v[nt]   = sh_aw2[nt * 16 + col];
        }
        #pragma unroll
        for (int i = 0; i < 4; ++i) {
            float p = 0.f;
            #pragma unroll
            for (int nt = 0; nt < 5; ++nt) {
                float u = acc[mi][nt][i] + bias_v[nt];
                p += fmaxf(u, 0.f) * a2_v[nt];
            }
            p += __shfl_xor(p, 1);
            p += __shfl_xor(p, 2);
            p += __shfl_xor(p, 4);
            p += __shfl_xor(p, 8);
            if (col == 0) sh_sc[bl][lbase + i] = p;
        }
    }
    __syncthreads();

    // ---- phase 4: masked softmax + att + combined ----
    if (wv < 2) {
        int b = b0 + wv;
        float sc = -INFINITY;
        if (lane < LHIST) {
            sc = sh_sc[wv][lane];
            if (hg[b * LHIST + lane] == 0) sc = -1e9f;
        }
        float m = sc;
        #pragma unroll
        for (int off = 32; off > 0; off >>= 1) m = fmaxf(m, __shfl_xor(m, off));
        float e = (lane < LHIST) ? __expf(sc - m) : 0.f;
        float ssum = e;
        #pragma unroll
        for (int off = 32; off > 0; off >>= 1) ssum += __shfl_xor(ssum, off);
        float w = e / ssum;

        // element (row m, k=lane) in frag layout
        int kbase = ((lane >> 5) * 64 + ((lane >> 3) & 3) * 16) * 8 + (lane & 7);
        float att = 0.f;
        #pragma unroll 5
        for (int l = 0; l < LHIST; ++l) {
            int m2 = wv * 64 + l;
            float wl = __shfl(w, l);
            att += wl * bf2f(sh_A[(m2 >> 4) * 1024 + kbase + (m2 & 15) * 8]);
        }
        float* crow = combined + (size_t)b * 160;
        crow[32 + lane] = sh_q[wv][lane];
        crow[96 + lane] = att;
        if (lane < 32) crow[lane] = user_table[(size_t)cid[b] * 32 + lane];
    }
}

// ---------- MLP: MFMA, 32 batch rows per 256-thread block ----------
__global__ void __launch_bounds__(256, 4) mlp_kernel(
    const float* __restrict__ combined,
    const unsigned short* __restrict__ W1f, const unsigned short* __restrict__ W2f,
    const float* __restrict__ mb1, const float* __restrict__ mb2,
    const float* __restrict__ mw3, const float* __restrict__ mb3,
    float* __restrict__ out)
{
    __shared__ __align__(16) unsigned short shA1[5120];   // [mt2][ks5][lane][8]
    __shared__ __align__(16) unsigned short shA2[8192];   // [mt2][ks8][lane][8]
    __shared__ float sh_part[4][32];

    const int t = threadIdx.x;
    const int b0 = blockIdx.x * 32;
    const int wv = t >> 6;
    const int lane = t & 63;
    const int quad = lane >> 4;
    const int col = lane & 15;

    // pack A1 = combined bf16 frags
    for (int i = t; i < 1280; i += 256) {
        int m = i / 40;
        int s = i - m * 40;
        int k0 = s * 4;
        float4 v = *(const float4*)&combined[(size_t)(b0 + m) * 160 + k0];
        int mt = m >> 4, colm = m & 15;
        int ks = k0 >> 5, qd = (k0 >> 3) & 3, off = k0 & 7;
        ushort4 r; r.x = f2bf(v.x); r.y = f2bf(v.y); r.z = f2bf(v.z); r.w = f2bf(v.w);
        *(ushort4*)&shA1[((mt * 5 + ks) * 64 + qd * 16 + colm) * 8 + off] = r;
    }
    __syncthreads();

    // layer 1: z1[32][256], wave wv owns n-tiles wv*4..wv*4+3
    f32x4 acc1[2][4];
    #pragma unroll
    for (int mt = 0; mt < 2; ++mt)
        #pragma unroll
        for (int j = 0; j < 4; ++j) acc1[mt][j] = (f32x4){0.f, 0.f, 0.f, 0.f};
    #pragma unroll
    for (int ks = 0; ks < 5; ++ks) {
        bf16x8 a0 = *(const bf16x8*)&shA1[(ks * 64 + lane) * 8];
        bf16x8 a1 = *(const bf16x8*)&shA1[((5 + ks) * 64 + lane) * 8];
        #pragma unroll
        for (int j = 0; j < 4; ++j) {
            int ntg = wv * 4 + j;
            bf16x8 b = *(const bf16x8*)&W1f[((ntg * 5 + ks) * 64 + lane) * 8];
            acc1[0][j] = __builtin_amdgcn_mfma_f32_16x16x32_bf16(a0, b, acc1[0][j], 0, 0, 0);
            acc1[1][j] = __builtin_amdgcn_mfma_f32_16x16x32_bf16(a1, b, acc1[1][j], 0, 0, 0);
        }
    }
    // epilogue 1: relu + bias -> shA2 (transpose to A-frag layout)
    #pragma unroll
    for (int j = 0; j < 4; ++j) {
        int n = (wv * 4 + j) * 16 + col;
        float bj = mb1[n];
        int ks2 = n >> 5, qd2 = (n >> 3) & 3, off2 = n & 7;
        #pragma unroll
        for (int mt = 0; mt < 2; ++mt)
            #pragma unroll
            for (int i = 0; i < 4; ++i) {
                float z = fmaxf(acc1[mt][j][i] + bj, 0.f);
                shA2[((mt * 8 + ks2) * 64 + qd2 * 16 + quad * 4 + i) * 8 + off2] = f2bf(z);
            }
    }
    __syncthreads();

    // layer 2: z2[32][128], wave owns n-tiles wv*2, wv*2+1
    f32x4 acc2[2][2];
    #pragma unroll
    for (int mt = 0; mt < 2; ++mt)
        #pragma unroll
        for (int jj = 0; jj < 2; ++jj) acc2[mt][jj] = (f32x4){0.f, 0.f, 0.f, 0.f};
    #pragma unroll
    for (int ks = 0; ks < 8; ++ks) {
        bf16x8 a0 = *(const bf16x8*)&shA2[(ks * 64 + lane) * 8];
        bf16x8 a1 = *(const bf16x8*)&shA2[((8 + ks) * 64 + lane) * 8];
        #pragma unroll
        for (int jj = 0; jj < 2; ++jj) {
            int ntg = wv * 2 + jj;
            bf16x8 b = *(const bf16x8*)&W2f[((ntg * 8 + ks) * 64 + lane) * 8];
            acc2[0][jj] = __builtin_amdgcn_mfma_f32_16x16x32_bf16(a0, b, acc2[0][jj], 0, 0, 0);
            acc2[1][jj] = __builtin_amdgcn_mfma_f32_16x16x32_bf16(a1, b, acc2[1][jj], 0, 0, 0);
        }
    }
    // layer 3: out = relu(z2+b2) . mw3, partial per wave then cross-wave sum
    #pragma unroll
    for (int mt = 0; mt < 2; ++mt) {
        #pragma unroll
        for (int i = 0; i < 4; ++i) {
            float p = 0.f;
            #pragma unroll
            for (int jj = 0; jj < 2; ++jj) {
                int n = (wv * 2 + jj) * 16 + col;
                float z = fmaxf(acc2[mt][jj][i] + mb2[n], 0.f);
                p += z * mw3[n];
            }
            p += __shfl_xor(p, 1);
            p += __shfl_xor(p, 2);
            p += __shfl_xor(p, 4);
            p += __shfl_xor(p, 8);
            if (col == 0) sh_part[wv][mt * 16 + quad * 4 + i] = p;
        }
    }
    __syncthreads();
    if (t < 32)
        out[b0 + t] = sh_part[0][t] + sh_part[1][t] + sh_part[2][t] + sh_part[3][t] + mb3[0];
}

extern "C" void kernel_launch(void* const* d_in, const int* in_sizes, int n_in,
                              void* d_out, int out_size, void* d_ws, size_t ws_size,
                              hipStream_t stream) {
    const int*   cid = (const int*)d_in[0];
    const int*   cg  = (const int*)d_in[1];
    const int*   cc  = (const int*)d_in[2];
    const int*   hg  = (const int*)d_in[3];
    const int*   hc  = (const int*)d_in[4];
    const float* user_table = (const float*)d_in[5];
    const float* item_table = (const float*)d_in[6];
    const float* cat_table  = (const float*)d_in[7];
    const float* aw1 = (const float*)d_in[8];
    const float* ab1 = (const float*)d_in[9];
    const float* aw2 = (const float*)d_in[10];
    const float* mw1 = (const float*)d_in[12];
    const float* mb1 = (const float*)d_in[13];
    const float* mw2 = (const float*)d_in[14];
    const float* mb2 = (const float*)d_in[15];
    const float* mw3 = (const float*)d_in[16];
    const float* mb3 = (const float*)d_in[17];
    float* out = (float*)d_out;

    const int B = in_sizes[0];                    // 16384
    float* ws = (float*)d_ws;
    float* Awt = ws;
    float* Bmf = ws + 5120;
    float* W4f = ws + 10240;
    unsigned short* W1f = (unsigned short*)(ws + 15360);
    unsigned short* W2f = (unsigned short*)(ws + 35840);
    float* combined = ws + 52224;

    prep_kernel<<<160, 256, 0, stream>>>(aw1, mw1, mw2, Awt, Bmf, W4f, W1f, W2f);
    attn_kernel<<<B / 2, 256, 0, stream>>>(cid, cg, cc, hg, hc,
                                           user_table, item_table, cat_table,
                                           ab1, aw2, Awt, Bmf, W4f, combined);
    mlp_kernel<<<B / 32, 256, 0, stream>>>(combined, W1f, W2f,
                                           mb1, mb2, mw3, mb3, out);
}

// Round 4
// 239.024 us; speedup vs baseline: 1.8177x; 1.0473x over previous
//
#include <hip/hip_runtime.h>
#include <math.h>

#define LHIST 50

typedef __attribute__((ext_vector_type(8))) short bf16x8;
typedef __attribute__((ext_vector_type(4))) float f32x4;

__device__ __forceinline__ unsigned short f2bf(float f) {
    union { float f; unsigned u; } v; v.f = f;
    unsigned r = v.u + 0x7fff + ((v.u >> 16) & 1);   // RNE
    return (unsigned short)(r >> 16);
}
__device__ __forceinline__ float bf2f(unsigned short h) {
    union { unsigned u; float f; } v; v.u = ((unsigned)h) << 16;
    return v.f;
}

// ws float offsets:
//  Awt    [80][64] fp32                   @ 0         (5120)
//  Bmfb   frag bf16 [nt5][ks2][lane][8]   @ 5120      (2560 f)
//  W4fb   frag bf16 [nt5][ks2][lane][8]   @ 7680      (2560 f)
//  W1f    frag bf16 [nt16][ks5][lane][8]  @ 10240     (20480 f)
//  W2f    frag bf16 [nt8][ks8][lane][8]   @ 30720     (16384 f)
//  itemb  bf16 [NI*32]                    @ 47104     (NI*16 f)
//  catb   bf16 [NC*32]                    @ 47104+NI*16
//  combined [B][160] fp32                 after catb

__global__ void prep_kernel(const float* __restrict__ aw1,
                            const float* __restrict__ mw1,
                            const float* __restrict__ mw2,
                            const float* __restrict__ item_table,
                            const float* __restrict__ cat_table,
                            int itemN, int catN,
                            float* __restrict__ Awt,
                            unsigned short* __restrict__ Bmfb,
                            unsigned short* __restrict__ W4fb,
                            unsigned short* __restrict__ W1f,
                            unsigned short* __restrict__ W2f,
                            unsigned short* __restrict__ itemb,
                            unsigned short* __restrict__ catb) {
    int i = blockIdx.x * 256 + threadIdx.x;
    if (i < itemN) itemb[i] = f2bf(item_table[i]);
    if (i < catN)  catb[i]  = f2bf(cat_table[i]);
    if (i < 5120) {
        int j = i >> 6, k = i & 63;
        Awt[i] = aw1[k * 80 + j] + aw1[(128 + k) * 80 + j];     // (W1+W3)^T
        int off = i & 7, lane = (i >> 3) & 63, ks = (i >> 9) & 1, nt = i >> 10;
        int n = nt * 16 + (lane & 15);
        int kk = ks * 32 + (lane >> 4) * 8 + off;
        Bmfb[i] = f2bf(aw1[(64 + kk) * 80 + n] - aw1[(128 + kk) * 80 + n]);  // W2-W3
        W4fb[i] = f2bf(aw1[(192 + kk) * 80 + n]);
    }
    if (i < 40960) {
        int off = i & 7, lane = (i >> 3) & 63;
        int rest = i >> 9; int ks = rest % 5, nt = rest / 5;
        int n = nt * 16 + (lane & 15);
        int kk = ks * 32 + (lane >> 4) * 8 + off;
        W1f[i] = f2bf(mw1[kk * 256 + n]);
    }
    if (i < 32768) {
        int off = i & 7, lane = (i >> 3) & 63;
        int rest = i >> 9; int ks = rest & 7, nt = rest >> 3;
        int n = nt * 16 + (lane & 15);
        int kk = ks * 32 + (lane >> 4) * 8 + off;
        W2f[i] = f2bf(mw2[kk * 128 + n]);
    }
}

// ---------- attention: 2 batch rows / 256-thread block ----------
__global__ void __launch_bounds__(256, 4) attn_kernel(
    const int* __restrict__ cid, const int* __restrict__ cg,
    const int* __restrict__ cc,  const int* __restrict__ hg,
    const int* __restrict__ hc,
    const float* __restrict__ user_table, const float* __restrict__ item_table,
    const float* __restrict__ cat_table,
    const float* __restrict__ ab1, const float* __restrict__ aw2,
    const float* __restrict__ Awt, const unsigned short* __restrict__ Bmfb,
    const unsigned short* __restrict__ W4fb,
    const unsigned short* __restrict__ itemb, const unsigned short* __restrict__ catb,
    float* __restrict__ combined)
{
    __shared__ __align__(16) unsigned short sh_A[8192];        // [mt8][ks2][lane][8]
    __shared__ __align__(16) unsigned short sh_Bq[2][5120];    // [b][nt5][ks2][lane][8]
    __shared__ __align__(16) float sh_q[2][64];
    __shared__ float sh_bias[2][80];
    __shared__ float sh_sc[2][64];
    __shared__ float sh_aw2[80];
    __shared__ __align__(16) float sh_att[2][2][64];

    const int t = threadIdx.x;
    const int b0 = blockIdx.x * 2;

    // ---- phase 0: q (fp32 tables), aw2 ----
    if (t < 128) {
        int qbi = t >> 6, k = t & 63;
        int b = b0 + qbi;
        float v = (k < 32) ? item_table[(size_t)cg[b] * 32 + k]
                           : cat_table[(size_t)cc[b] * 32 + (k - 32)];
        sh_q[qbi][k] = v;
    }
    if (t < 80) sh_aw2[t] = aw2[t];
    __syncthreads();

    // ---- phase 1a: gather bf16 hist rows -> A frags (pure copy, zero-fill l>=50) ----
    for (int i = t; i < 1024; i += 256) {
        int gbi = i >> 9;
        int rem = i & 511;
        int l = rem >> 3;            // 0..63
        int c = rem & 7;             // chunk
        int half = c >> 2, s = c & 3;
        uint4 v = make_uint4(0, 0, 0, 0);
        if (l < LHIST) {
            int b = b0 + gbi;
            int idx = (half ? hc : hg)[b * LHIST + l];
            v = *(const uint4*)&(half ? catb : itemb)[(size_t)idx * 32 + s * 8];
        }
        int m = gbi * 64 + l;
        int mt = m >> 4, colm = m & 15;
        *(uint4*)&sh_A[((mt * 2 + half) * 64 + s * 16 + colm) * 8] = v;
    }
    // ---- phase 1b: B' = Bm + diag(q).W4 (bf16 sources), frag-packed ----
    for (int i8 = t; i8 < 1280; i8 += 256) {
        int b = i8 >= 640;
        int base = (i8 - b * 640) * 8;           // element index in [0,5120)
        int lane8 = (base >> 3) & 63, ks = (base >> 9) & 1;
        int kk = ks * 32 + (lane8 >> 4) * 8;
        uint4 bm4 = *(const uint4*)&Bmfb[base];
        uint4 w44 = *(const uint4*)&W4fb[base];
        float4 qa = *(const float4*)&sh_q[b][kk];
        float4 qb = *(const float4*)&sh_q[b][kk + 4];
        unsigned bmw[4] = {bm4.x, bm4.y, bm4.z, bm4.w};
        unsigned w4w[4] = {w44.x, w44.y, w44.z, w44.w};
        float qv[8] = {qa.x, qa.y, qa.z, qa.w, qb.x, qb.y, qb.z, qb.w};
        unsigned res[4];
        #pragma unroll
        for (int d = 0; d < 4; ++d) {
            float b_lo = bf2f((unsigned short)(bmw[d] & 0xffff));
            float b_hi = bf2f((unsigned short)(bmw[d] >> 16));
            float w_lo = bf2f((unsigned short)(w4w[d] & 0xffff));
            float w_hi = bf2f((unsigned short)(w4w[d] >> 16));
            unsigned short r_lo = f2bf(b_lo + qv[2 * d] * w_lo);
            unsigned short r_hi = f2bf(b_hi + qv[2 * d + 1] * w_hi);
            res[d] = (unsigned)r_lo | ((unsigned)r_hi << 16);
        }
        *(uint4*)&sh_Bq[b][base] = make_uint4(res[0], res[1], res[2], res[3]);
    }
    // ---- phase 1c: bias[b][j] = ab1[j] + q.(W1+W3)[:,j] (fp32 exact) ----
    if (t < 160) {
        int bi = t >= 80;
        int j = t - bi * 80;
        float s = ab1[j];
        const float4* aw = (const float4*)&Awt[j * 64];
        #pragma unroll
        for (int k4 = 0; k4 < 16; ++k4) {
            float4 a = aw[k4];
            float4 q = *(const float4*)&sh_q[bi][k4 * 4];
            s += a.x * q.x + a.y * q.y + a.z * q.z + a.w * q.w;
        }
        sh_bias[bi][j] = s;
    }
    __syncthreads();

    // ---- phase 2: MFMA u[128][80] = A[128x64] @ B'[64x80] ----
    const int wv = t >> 6;
    const int lane = t & 63;
    const int quad = lane >> 4;
    const int col = lane & 15;
    const int bb = wv >> 1;

    f32x4 acc[2][5];
    #pragma unroll
    for (int mi = 0; mi < 2; ++mi)
        #pragma unroll
        for (int nt = 0; nt < 5; ++nt)
            acc[mi][nt] = (f32x4){0.f, 0.f, 0.f, 0.f};

    #pragma unroll
    for (int ks = 0; ks < 2; ++ks) {
        bf16x8 a0 = *(const bf16x8*)&sh_A[(((2 * wv) * 2 + ks) * 64 + lane) * 8];
        bf16x8 a1 = *(const bf16x8*)&sh_A[(((2 * wv + 1) * 2 + ks) * 64 + lane) * 8];
        #pragma unroll
        for (int nt = 0; nt < 5; ++nt) {
            bf16x8 bfr = *(const bf16x8*)&sh_Bq[bb][((nt * 2 + ks) * 64 + lane) * 8];
            acc[0][nt] = __builtin_amdgcn_mfma_f32_16x16x32_bf16(a0, bfr, acc[0][nt], 0, 0, 0);
            acc[1][nt] = __builtin_amdgcn_mfma_f32_16x16x32_bf16(a1, bfr, acc[1][nt], 0, 0, 0);
        }
    }

    // ---- phase 3: scores = relu(u+bias).aw2, reduce over 16 col lanes ----
    #pragma unroll
    for (int mi = 0; mi < 2; ++mi) {
        int mt = 2 * wv + mi;
        int bl = mt >> 2;
        int lbase = (mt & 3) * 16 + quad * 4;
        float bias_v[5], a2_v[5];
        #pragma unroll
        for (int nt = 0; nt < 5; ++nt) {
            bias_v[nt] = sh_bias[bl][nt * 16 + col];
            a2_v[nt]   = sh_aw2[nt * 16 + col];
        }
        #pragma unroll
        for (int i = 0; i < 4; ++i) {
            float p = 0.f;
            #pragma unroll
            for (int nt = 0; nt < 5; ++nt) {
                float u = acc[mi][nt][i] + bias_v[nt];
                p += fmaxf(u, 0.f) * a2_v[nt];
            }
            p += __shfl_xor(p, 1);
            p += __shfl_xor(p, 2);
            p += __shfl_xor(p, 4);
            p += __shfl_xor(p, 8);
            if (col == 0) sh_sc[bl][lbase + i] = p;
        }
    }
    __syncthreads();

    // ---- phase 4: softmax (per wave) + att (4 waves, b128 conflict-free reads) ----
    {
        int batch = wv >> 1, half = wv & 1;
        int b = b0 + batch;
        float sc = -INFINITY;
        if (lane < LHIST) {
            sc = sh_sc[batch][lane];
            if (hg[b * LHIST + lane] == 0) sc = -1e9f;
        }
        float m = sc;
        #pragma unroll
        for (int off = 32; off > 0; off >>= 1) m = fmaxf(m, __shfl_xor(m, off));
        float e = (lane < LHIST) ? __expf(sc - m) : 0.f;
        float ssum = e;
        #pragma unroll
        for (int off = 32; off > 0; off >>= 1) ssum += __shfl_xor(ssum, off);
        float w = e / ssum;    // 0 for lane >= LHIST

        int c = lane & 7, lgrp = lane >> 3;
        float at[8];
        #pragma unroll
        for (int j = 0; j < 8; ++j) at[j] = 0.f;
        int ks = c >> 2, qd = c & 3;
        #pragma unroll
        for (int it = 0; it < 4; ++it) {
            int l = half * 32 + it * 8 + lgrp;
            float wl = __shfl(w, l);
            int m2 = batch * 64 + l;
            int mt = m2 >> 4, colm = m2 & 15;
            bf16x8 h = *(const bf16x8*)&sh_A[((mt * 2 + ks) * 64 + qd * 16 + colm) * 8];
            #pragma unroll
            for (int j = 0; j < 8; ++j)
                at[j] += wl * bf2f((unsigned short)h[j]);
        }
        #pragma unroll
        for (int off = 8; off < 64; off <<= 1)
            #pragma unroll
            for (int j = 0; j < 8; ++j) at[j] += __shfl_xor(at[j], off);
        if (lane < 8) {   // d = lane*8 + j
            *(float4*)&sh_att[batch][half][lane * 8]     = make_float4(at[0], at[1], at[2], at[3]);
            *(float4*)&sh_att[batch][half][lane * 8 + 4] = make_float4(at[4], at[5], at[6], at[7]);
        }
    }
    __syncthreads();

    // ---- phase 5: write combined ----
    if (wv < 2) {
        int b = b0 + wv;
        float att = sh_att[wv][0][lane] + sh_att[wv][1][lane];
        float* crow = combined + (size_t)b * 160;
        crow[32 + lane] = sh_q[wv][lane];
        crow[96 + lane] = att;
        if (lane < 32) crow[lane] = user_table[(size_t)cid[b] * 32 + lane];
    }
}

// ---------- MLP: MFMA, 64 batch rows per 256-thread block ----------
__global__ void __launch_bounds__(256) mlp_kernel(
    const float* __restrict__ combined,
    const unsigned short* __restrict__ W1f, const unsigned short* __restrict__ W2f,
    const float* __restrict__ mb1, const float* __restrict__ mb2,
    const float* __restrict__ mw3, const float* __restrict__ mb3,
    float* __restrict__ out)
{
    __shared__ __align__(16) unsigned short shA1[10240];  // [mt4][ks5][lane][8]
    __shared__ __align__(16) unsigned short shA2[16384];  // [mt4][ks8][lane][8]
    __shared__ float sh_part[4][64];

    const int t = threadIdx.x;
    const int b0 = blockIdx.x * 64;
    const int wv = t >> 6;
    const int lane = t & 63;
    const int quad = lane >> 4;
    const int col = lane & 15;

    // pack A1 = combined bf16 frags (64 batches x 40 float4 chunks)
    for (int i = t; i < 2560; i += 256) {
        int m = i / 40;
        int s = i - m * 40;
        int k0 = s * 4;
        float4 v = *(const float4*)&combined[(size_t)(b0 + m) * 160 + k0];
        int mt = m >> 4, colm = m & 15;
        int ks = k0 >> 5, qd = (k0 >> 3) & 3, off = k0 & 7;
        ushort4 r; r.x = f2bf(v.x); r.y = f2bf(v.y); r.z = f2bf(v.z); r.w = f2bf(v.w);
        *(ushort4*)&shA1[((mt * 5 + ks) * 64 + qd * 16 + colm) * 8 + off] = r;
    }
    __syncthreads();

    // layer 1: z1[64][256], wave wv owns n-tiles wv*4..wv*4+3
    f32x4 acc1[4][4];
    #pragma unroll
    for (int mt = 0; mt < 4; ++mt)
        #pragma unroll
        for (int j = 0; j < 4; ++j) acc1[mt][j] = (f32x4){0.f, 0.f, 0.f, 0.f};
    #pragma unroll
    for (int ks = 0; ks < 5; ++ks) {
        bf16x8 a[4];
        #pragma unroll
        for (int mt = 0; mt < 4; ++mt)
            a[mt] = *(const bf16x8*)&shA1[((mt * 5 + ks) * 64 + lane) * 8];
        #pragma unroll
        for (int j = 0; j < 4; ++j) {
            int ntg = wv * 4 + j;
            bf16x8 b = *(const bf16x8*)&W1f[((ntg * 5 + ks) * 64 + lane) * 8];
            #pragma unroll
            for (int mt = 0; mt < 4; ++mt)
                acc1[mt][j] = __builtin_amdgcn_mfma_f32_16x16x32_bf16(a[mt], b, acc1[mt][j], 0, 0, 0);
        }
    }
    // epilogue 1: relu + bias -> shA2 (transpose to A-frag layout)
    #pragma unroll
    for (int j = 0; j < 4; ++j) {
        int n = (wv * 4 + j) * 16 + col;
        float bj = mb1[n];
        int ks2 = n >> 5, qd2 = (n >> 3) & 3, off2 = n & 7;
        #pragma unroll
        for (int mt = 0; mt < 4; ++mt)
            #pragma unroll
            for (int i = 0; i < 4; ++i) {
                float z = fmaxf(acc1[mt][j][i] + bj, 0.f);
                shA2[((mt * 8 + ks2) * 64 + qd2 * 16 + quad * 4 + i) * 8 + off2] = f2bf(z);
            }
    }
    __syncthreads();

    // layer 2: z2[64][128], wave owns n-tiles wv*2, wv*2+1
    f32x4 acc2[4][2];
    #pragma unroll
    for (int mt = 0; mt < 4; ++mt)
        #pragma unroll
        for (int jj = 0; jj < 2; ++jj) acc2[mt][jj] = (f32x4){0.f, 0.f, 0.f, 0.f};
    #pragma unroll
    for (int ks = 0; ks < 8; ++ks) {
        bf16x8 a[4];
        #pragma unroll
        for (int mt = 0; mt < 4; ++mt)
            a[mt] = *(const bf16x8*)&shA2[((mt * 8 + ks) * 64 + lane) * 8];
        #pragma unroll
        for (int jj = 0; jj < 2; ++jj) {
            int ntg = wv * 2 + jj;
            bf16x8 b = *(const bf16x8*)&W2f[((ntg * 8 + ks) * 64 + lane) * 8];
            #pragma unroll
            for (int mt = 0; mt < 4; ++mt)
                acc2[mt][jj] = __builtin_amdgcn_mfma_f32_16x16x32_bf16(a[mt], b, acc2[mt][jj], 0, 0, 0);
        }
    }
    // layer 3: out = relu(z2+b2) . mw3, partial per wave then cross-wave sum
    #pragma unroll
    for (int mt = 0; mt < 4; ++mt) {
        #pragma unroll
        for (int i = 0; i < 4; ++i) {
            float p = 0.f;
            #pragma unroll
            for (int jj = 0; jj < 2; ++jj) {
                int n = (wv * 2 + jj) * 16 + col;
                float z = fmaxf(acc2[mt][jj][i] + mb2[n], 0.f);
                p += z * mw3[n];
            }
            p += __shfl_xor(p, 1);
            p += __shfl_xor(p, 2);
            p += __shfl_xor(p, 4);
            p += __shfl_xor(p, 8);
            if (col == 0) sh_part[wv][mt * 16 + quad * 4 + i] = p;
        }
    }
    __syncthreads();
    if (t < 64)
        out[b0 + t] = sh_part[0][t] + sh_part[1][t] + sh_part[2][t] + sh_part[3][t] + mb3[0];
}

extern "C" void kernel_launch(void* const* d_in, const int* in_sizes, int n_in,
                              void* d_out, int out_size, void* d_ws, size_t ws_size,
                              hipStream_t stream) {
    const int*   cid = (const int*)d_in[0];
    const int*   cg  = (const int*)d_in[1];
    const int*   cc  = (const int*)d_in[2];
    const int*   hg  = (const int*)d_in[3];
    const int*   hc  = (const int*)d_in[4];
    const float* user_table = (const float*)d_in[5];
    const float* item_table = (const float*)d_in[6];
    const float* cat_table  = (const float*)d_in[7];
    const float* aw1 = (const float*)d_in[8];
    const float* ab1 = (const float*)d_in[9];
    const float* aw2 = (const float*)d_in[10];
    const float* mw1 = (const float*)d_in[12];
    const float* mb1 = (const float*)d_in[13];
    const float* mw2 = (const float*)d_in[14];
    const float* mb2 = (const float*)d_in[15];
    const float* mw3 = (const float*)d_in[16];
    const float* mb3 = (const float*)d_in[17];
    float* out = (float*)d_out;

    const int B = in_sizes[0];                    // 16384
    const int itemN = in_sizes[6];                // NI*32
    const int catN  = in_sizes[7];                // NC*32
    float* ws = (float*)d_ws;
    float* Awt = ws;
    unsigned short* Bmfb = (unsigned short*)(ws + 5120);
    unsigned short* W4fb = (unsigned short*)(ws + 7680);
    unsigned short* W1f  = (unsigned short*)(ws + 10240);
    unsigned short* W2f  = (unsigned short*)(ws + 30720);
    unsigned short* itemb = (unsigned short*)(ws + 47104);
    unsigned short* catb  = itemb + itemN;
    float* combined = ws + 47104 + (itemN + catN + 1) / 2;

    int prep_grid = (itemN + 255) / 256;
    prep_kernel<<<prep_grid, 256, 0, stream>>>(aw1, mw1, mw2, item_table, cat_table,
                                               itemN, catN, Awt, Bmfb, W4fb, W1f, W2f,
                                               itemb, catb);
    attn_kernel<<<B / 2, 256, 0, stream>>>(cid, cg, cc, hg, hc,
                                           user_table, item_table, cat_table,
                                           ab1, aw2, Awt, Bmfb, W4fb, itemb, catb, combined);
    mlp_kernel<<<B / 64, 256, 0, stream>>>(combined, W1f, W2f,
                                           mb1, mb2, mw3, mb3, out);
}

// Round 5
// 198.682 us; speedup vs baseline: 2.1868x; 1.2030x over previous
//
#include <hip/hip_runtime.h>
#include <math.h>

#define LHIST 50

typedef __attribute__((ext_vector_type(8))) short bf16x8;
typedef __attribute__((ext_vector_type(4))) float f32x4;

__device__ __forceinline__ unsigned short f2bf(float f) {
    union { float f; unsigned u; } v; v.f = f;
    unsigned r = v.u + 0x7fff + ((v.u >> 16) & 1);   // RNE
    return (unsigned short)(r >> 16);
}
__device__ __forceinline__ float bf2f(unsigned short h) {
    union { unsigned u; float f; } v; v.u = ((unsigned)h) << 16;
    return v.f;
}

// ws float offsets:
//  Awt    [80][64] fp32                   @ 0         (5120)
//  Bmfb   frag bf16 [nt5][ks2][lane][8]   @ 5120      (2560 f)
//  W4fb   frag bf16 [nt5][ks2][lane][8]   @ 7680      (2560 f)
//  W1f    frag bf16 [nt16][ks5][lane][8]  @ 10240     (20480 f)
//  W2f    frag bf16 [nt8][ks8][lane][8]   @ 30720     (16384 f)
//  itemb  bf16 [NI*32]                    @ 47104     (NI*16 f)
//  catb   bf16 [NC*32]                    @ 47104+NI*16
//  combined [B][160] fp32                 after catb

__global__ void prep_kernel(const float* __restrict__ aw1,
                            const float* __restrict__ mw1,
                            const float* __restrict__ mw2,
                            const float* __restrict__ item_table,
                            const float* __restrict__ cat_table,
                            int itemN, int catN,
                            float* __restrict__ Awt,
                            unsigned short* __restrict__ Bmfb,
                            unsigned short* __restrict__ W4fb,
                            unsigned short* __restrict__ W1f,
                            unsigned short* __restrict__ W2f,
                            unsigned short* __restrict__ itemb,
                            unsigned short* __restrict__ catb) {
    int i = blockIdx.x * 256 + threadIdx.x;
    // vectorized table conversion: 8 elems/thread, coalesced
    int i8 = i * 8;
    if (i8 + 7 < itemN) {
        float4 a = *(const float4*)&item_table[i8];
        float4 b = *(const float4*)&item_table[i8 + 4];
        ushort4 lo, hi;
        lo.x = f2bf(a.x); lo.y = f2bf(a.y); lo.z = f2bf(a.z); lo.w = f2bf(a.w);
        hi.x = f2bf(b.x); hi.y = f2bf(b.y); hi.z = f2bf(b.z); hi.w = f2bf(b.w);
        *(ushort4*)&itemb[i8] = lo;
        *(ushort4*)&itemb[i8 + 4] = hi;
    }
    if (i8 + 7 < catN) {
        float4 a = *(const float4*)&cat_table[i8];
        float4 b = *(const float4*)&cat_table[i8 + 4];
        ushort4 lo, hi;
        lo.x = f2bf(a.x); lo.y = f2bf(a.y); lo.z = f2bf(a.z); lo.w = f2bf(a.w);
        hi.x = f2bf(b.x); hi.y = f2bf(b.y); hi.z = f2bf(b.z); hi.w = f2bf(b.w);
        *(ushort4*)&catb[i8] = lo;
        *(ushort4*)&catb[i8 + 4] = hi;
    }
    if (i < 5120) {
        int j = i >> 6, k = i & 63;
        Awt[i] = aw1[k * 80 + j] + aw1[(128 + k) * 80 + j];     // (W1+W3)^T
        // coalesced-read variant for Bmfb/W4fb: i = kk*80 + n
        int kk = i / 80, n = i - kk * 80;
        int nt = n >> 4, colw = n & 15, ks = kk >> 5, r = kk & 31, qd = r >> 3, off = r & 7;
        int d = ((nt * 2 + ks) * 64 + qd * 16 + colw) * 8 + off;
        Bmfb[d] = f2bf(aw1[(64 + kk) * 80 + n] - aw1[(128 + kk) * 80 + n]);  // W2-W3
        W4fb[d] = f2bf(aw1[(192 + kk) * 80 + n]);
    }
    if (i < 40960) {   // i = kk*256 + n : coalesced mw1 read, scattered frag write
        int kk = i >> 8, n = i & 255;
        int nt = n >> 4, colw = n & 15, ks = kk >> 5, r = kk & 31, qd = r >> 3, off = r & 7;
        W1f[((nt * 5 + ks) * 64 + qd * 16 + colw) * 8 + off] = f2bf(mw1[i]);
    }
    if (i < 32768) {   // i = kk*128 + n
        int kk = i >> 7, n = i & 127;
        int nt = n >> 4, colw = n & 15, ks = kk >> 5, r = kk & 31, qd = r >> 3, off = r & 7;
        W2f[((nt * 8 + ks) * 64 + qd * 16 + colw) * 8 + off] = f2bf(mw2[i]);
    }
}

// ---------- attention: 2 batch rows / 256-thread block, A gathered to regs ----------
__global__ void __launch_bounds__(256, 6) attn_kernel(
    const int* __restrict__ cid, const int* __restrict__ cg,
    const int* __restrict__ cc,  const int* __restrict__ hg,
    const int* __restrict__ hc,
    const float* __restrict__ user_table, const float* __restrict__ item_table,
    const float* __restrict__ cat_table,
    const float* __restrict__ ab1, const float* __restrict__ aw2,
    const float* __restrict__ Awt, const unsigned short* __restrict__ Bmfb,
    const unsigned short* __restrict__ W4fb,
    const unsigned short* __restrict__ itemb, const unsigned short* __restrict__ catb,
    float* __restrict__ combined)
{
    __shared__ __align__(16) unsigned short sh_Bq[2][5120];    // [b][nt5][ks2][lane][8]
    __shared__ __align__(16) float sh_q[2][64];
    __shared__ float sh_bias[2][80];
    __shared__ float sh_sc[2][64];
    __shared__ float sh_aw2[80];
    __shared__ __align__(16) float sh_att[2][2][64];

    const int t = threadIdx.x;
    const int b0 = blockIdx.x * 2;
    const int wv = t >> 6;
    const int lane = t & 63;
    const int quad = lane >> 4;
    const int col = lane & 15;

    // ---- phase 0: q (fp32 tables), aw2 ----
    if (t < 128) {
        int qbi = t >> 6, k = t & 63;
        int b = b0 + qbi;
        float v = (k < 32) ? item_table[(size_t)cg[b] * 32 + k]
                           : cat_table[(size_t)cc[b] * 32 + (k - 32)];
        sh_q[qbi][k] = v;
    }
    if (t < 80) sh_aw2[t] = aw2[t];
    __syncthreads();

    // ---- phase 1: B' = Bm + diag(q).W4 (bf16), frag-packed; bias fp32 ----
    for (int i8 = t; i8 < 1280; i8 += 256) {
        int b = i8 >= 640;
        int base = (i8 - b * 640) * 8;
        int lane8 = (base >> 3) & 63, ks = (base >> 9) & 1;
        int kk = ks * 32 + (lane8 >> 4) * 8;
        uint4 bm4 = *(const uint4*)&Bmfb[base];
        uint4 w44 = *(const uint4*)&W4fb[base];
        float4 qa = *(const float4*)&sh_q[b][kk];
        float4 qb = *(const float4*)&sh_q[b][kk + 4];
        unsigned bmw[4] = {bm4.x, bm4.y, bm4.z, bm4.w};
        unsigned w4w[4] = {w44.x, w44.y, w44.z, w44.w};
        float qv[8] = {qa.x, qa.y, qa.z, qa.w, qb.x, qb.y, qb.z, qb.w};
        unsigned res[4];
        #pragma unroll
        for (int d = 0; d < 4; ++d) {
            float b_lo = bf2f((unsigned short)(bmw[d] & 0xffff));
            float b_hi = bf2f((unsigned short)(bmw[d] >> 16));
            float w_lo = bf2f((unsigned short)(w4w[d] & 0xffff));
            float w_hi = bf2f((unsigned short)(w4w[d] >> 16));
            unsigned short r_lo = f2bf(b_lo + qv[2 * d] * w_lo);
            unsigned short r_hi = f2bf(b_hi + qv[2 * d + 1] * w_hi);
            res[d] = (unsigned)r_lo | ((unsigned)r_hi << 16);
        }
        *(uint4*)&sh_Bq[b][base] = make_uint4(res[0], res[1], res[2], res[3]);
    }
    if (t < 160) {
        int bi = t >= 80;
        int j = t - bi * 80;
        float s = ab1[j];
        const float4* aw = (const float4*)&Awt[j * 64];
        #pragma unroll
        for (int k4 = 0; k4 < 16; ++k4) {
            float4 a = aw[k4];
            float4 q = *(const float4*)&sh_q[bi][k4 * 4];
            s += a.x * q.x + a.y * q.y + a.z * q.z + a.w * q.w;
        }
        sh_bias[bi][j] = s;
    }

    // ---- phase 2a: gather A-frags straight to registers (no LDS, no sync needed) ----
    const int bb = wv >> 1;      // batch of this wave
    const int hwv = wv & 1;      // which half of l-range
    const int b = b0 + bb;
    bf16x8 afr[2][2];            // [mi][ks]
    #pragma unroll
    for (int mi = 0; mi < 2; ++mi) {
        int l = hwv * 32 + mi * 16 + col;
        bool valid = (l < LHIST);
        int lc = valid ? l : 0;
        int idx_i = hg[b * LHIST + lc];
        int idx_c = hc[b * LHIST + lc];
        uint4 vi = *(const uint4*)&itemb[(size_t)idx_i * 32 + quad * 8];
        uint4 vc = *(const uint4*)&catb[(size_t)idx_c * 32 + quad * 8];
        if (!valid) { vi = make_uint4(0, 0, 0, 0); vc = make_uint4(0, 0, 0, 0); }
        afr[mi][0] = *(bf16x8*)&vi;
        afr[mi][1] = *(bf16x8*)&vc;
    }
    __syncthreads();

    // ---- phase 2b: MFMA u = A[2 tiles x K64] @ B'[64x80] ----
    f32x4 acc[2][5];
    #pragma unroll
    for (int mi = 0; mi < 2; ++mi)
        #pragma unroll
        for (int nt = 0; nt < 5; ++nt)
            acc[mi][nt] = (f32x4){0.f, 0.f, 0.f, 0.f};

    #pragma unroll
    for (int ks = 0; ks < 2; ++ks) {
        #pragma unroll
        for (int nt = 0; nt < 5; ++nt) {
            bf16x8 bfr = *(const bf16x8*)&sh_Bq[bb][((nt * 2 + ks) * 64 + lane) * 8];
            acc[0][nt] = __builtin_amdgcn_mfma_f32_16x16x32_bf16(afr[0][ks], bfr, acc[0][nt], 0, 0, 0);
            acc[1][nt] = __builtin_amdgcn_mfma_f32_16x16x32_bf16(afr[1][ks], bfr, acc[1][nt], 0, 0, 0);
        }
    }

    // ---- phase 3: scores = relu(u+bias).aw2, reduce over 16 col lanes ----
    {
        float bias_v[5], a2_v[5];
        #pragma unroll
        for (int nt = 0; nt < 5; ++nt) {
            bias_v[nt] = sh_bias[bb][nt * 16 + col];
            a2_v[nt]   = sh_aw2[nt * 16 + col];
        }
        #pragma unroll
        for (int mi = 0; mi < 2; ++mi) {
            int lbase = hwv * 32 + mi * 16 + quad * 4;
            #pragma unroll
            for (int i = 0; i < 4; ++i) {
                float p = 0.f;
                #pragma unroll
                for (int nt = 0; nt < 5; ++nt) {
                    float u = acc[mi][nt][i] + bias_v[nt];
                    p += fmaxf(u, 0.f) * a2_v[nt];
                }
                p += __shfl_xor(p, 1);
                p += __shfl_xor(p, 2);
                p += __shfl_xor(p, 4);
                p += __shfl_xor(p, 8);
                if (col == 0 && lbase + i < 64) sh_sc[bb][lbase + i] = p;
            }
        }
    }
    __syncthreads();

    // ---- phase 4: softmax (per wave) + att via L2-hot global re-gather ----
    {
        float sc = -INFINITY;
        if (lane < LHIST) {
            sc = sh_sc[bb][lane];
            if (hg[b * LHIST + lane] == 0) sc = -1e9f;
        }
        float m = sc;
        #pragma unroll
        for (int off = 32; off > 0; off >>= 1) m = fmaxf(m, __shfl_xor(m, off));
        float e = (lane < LHIST) ? __expf(sc - m) : 0.f;
        float ssum = e;
        #pragma unroll
        for (int off = 32; off > 0; off >>= 1) ssum += __shfl_xor(ssum, off);
        float w = e / ssum;    // 0 for lane >= LHIST

        int c = lane & 7, lgrp = lane >> 3;
        int isCat = c >> 2, s4 = c & 3;
        float at[8];
        #pragma unroll
        for (int j = 0; j < 8; ++j) at[j] = 0.f;
        #pragma unroll
        for (int it = 0; it < 4; ++it) {
            int l = hwv * 32 + it * 8 + lgrp;
            int lc = (l < LHIST) ? l : LHIST - 1;
            float wl = __shfl(w, l);           // 0 for l >= LHIST
            int idx = (isCat ? hc : hg)[b * LHIST + lc];
            uint4 hv = *(const uint4*)&(isCat ? catb : itemb)[(size_t)idx * 32 + s4 * 8];
            bf16x8 h = *(bf16x8*)&hv;
            #pragma unroll
            for (int j = 0; j < 8; ++j)
                at[j] += wl * bf2f((unsigned short)h[j]);
        }
        #pragma unroll
        for (int off = 8; off < 64; off <<= 1)
            #pragma unroll
            for (int j = 0; j < 8; ++j) at[j] += __shfl_xor(at[j], off);
        if (lane < 8) {   // d = (isCat*32 if lane>=4 handled by c mapping): d = c*8+j
            *(float4*)&sh_att[bb][hwv][lane * 8]     = make_float4(at[0], at[1], at[2], at[3]);
            *(float4*)&sh_att[bb][hwv][lane * 8 + 4] = make_float4(at[4], at[5], at[6], at[7]);
        }
    }
    __syncthreads();

    // ---- phase 5: write combined ----
    if (wv < 2) {
        int bo = b0 + wv;
        float att = sh_att[wv][0][lane] + sh_att[wv][1][lane];
        float* crow = combined + (size_t)bo * 160;
        crow[32 + lane] = sh_q[wv][lane];
        crow[96 + lane] = att;
        if (lane < 32) crow[lane] = user_table[(size_t)cid[bo] * 32 + lane];
    }
}

// ---------- MLP: MFMA, 32 batch rows per 256-thread block ----------
__global__ void __launch_bounds__(256, 4) mlp_kernel(
    const float* __restrict__ combined,
    const unsigned short* __restrict__ W1f, const unsigned short* __restrict__ W2f,
    const float* __restrict__ mb1, const float* __restrict__ mb2,
    const float* __restrict__ mw3, const float* __restrict__ mb3,
    float* __restrict__ out)
{
    __shared__ __align__(16) unsigned short shA1[5120];   // [mt2][ks5][lane][8]
    __shared__ __align__(16) unsigned short shA2[8192];   // [mt2][ks8][lane][8]
    __shared__ float sh_part[4][32];

    const int t = threadIdx.x;
    const int b0 = blockIdx.x * 32;
    const int wv = t >> 6;
    const int lane = t & 63;
    const int quad = lane >> 4;
    const int col = lane & 15;

    // pack A1 = combined bf16 frags
    for (int i = t; i < 1280; i += 256) {
        int m = i / 40;
        int s = i - m * 40;
        int k0 = s * 4;
        float4 v = *(const float4*)&combined[(size_t)(b0 + m) * 160 + k0];
        int mt = m >> 4, colm = m & 15;
        int ks = k0 >> 5, qd = (k0 >> 3) & 3, off = k0 & 7;
        ushort4 r; r.x = f2bf(v.x); r.y = f2bf(v.y); r.z = f2bf(v.z); r.w = f2bf(v.w);
        *(ushort4*)&shA1[((mt * 5 + ks) * 64 + qd * 16 + colm) * 8 + off] = r;
    }
    __syncthreads();

    // layer 1: z1[32][256], wave wv owns n-tiles wv*4..wv*4+3
    f32x4 acc1[2][4];
    #pragma unroll
    for (int mt = 0; mt < 2; ++mt)
        #pragma unroll
        for (int j = 0; j < 4; ++j) acc1[mt][j] = (f32x4){0.f, 0.f, 0.f, 0.f};
    #pragma unroll
    for (int ks = 0; ks < 5; ++ks) {
        bf16x8 a0 = *(const bf16x8*)&shA1[(ks * 64 + lane) * 8];
        bf16x8 a1 = *(const bf16x8*)&shA1[((5 + ks) * 64 + lane) * 8];
        #pragma unroll
        for (int j = 0; j < 4; ++j) {
            int ntg = wv * 4 + j;
            bf16x8 b = *(const bf16x8*)&W1f[((ntg * 5 + ks) * 64 + lane) * 8];
            acc1[0][j] = __builtin_amdgcn_mfma_f32_16x16x32_bf16(a0, b, acc1[0][j], 0, 0, 0);
            acc1[1][j] = __builtin_amdgcn_mfma_f32_16x16x32_bf16(a1, b, acc1[1][j], 0, 0, 0);
        }
    }
    // epilogue 1: relu + bias -> shA2 (transpose to A-frag layout)
    #pragma unroll
    for (int j = 0; j < 4; ++j) {
        int n = (wv * 4 + j) * 16 + col;
        float bj = mb1[n];
        int ks2 = n >> 5, qd2 = (n >> 3) & 3, off2 = n & 7;
        #pragma unroll
        for (int mt = 0; mt < 2; ++mt)
            #pragma unroll
            for (int i = 0; i < 4; ++i) {
                float z = fmaxf(acc1[mt][j][i] + bj, 0.f);
                shA2[((mt * 8 + ks2) * 64 + qd2 * 16 + quad * 4 + i) * 8 + off2] = f2bf(z);
            }
    }
    __syncthreads();

    // layer 2: z2[32][128], wave owns n-tiles wv*2, wv*2+1
    f32x4 acc2[2][2];
    #pragma unroll
    for (int mt = 0; mt < 2; ++mt)
        #pragma unroll
        for (int jj = 0; jj < 2; ++jj) acc2[mt][jj] = (f32x4){0.f, 0.f, 0.f, 0.f};
    #pragma unroll
    for (int ks = 0; ks < 8; ++ks) {
        bf16x8 a0 = *(const bf16x8*)&shA2[(ks * 64 + lane) * 8];
        bf16x8 a1 = *(const bf16x8*)&shA2[((8 + ks) * 64 + lane) * 8];
        #pragma unroll
        for (int jj = 0; jj < 2; ++jj) {
            int ntg = wv * 2 + jj;
            bf16x8 b = *(const bf16x8*)&W2f[((ntg * 8 + ks) * 64 + lane) * 8];
            acc2[0][jj] = __builtin_amdgcn_mfma_f32_16x16x32_bf16(a0, b, acc2[0][jj], 0, 0, 0);
            acc2[1][jj] = __builtin_amdgcn_mfma_f32_16x16x32_bf16(a1, b, acc2[1][jj], 0, 0, 0);
        }
    }
    // layer 3: out = relu(z2+b2) . mw3
    #pragma unroll
    for (int mt = 0; mt < 2; ++mt) {
        #pragma unroll
        for (int i = 0; i < 4; ++i) {
            float p = 0.f;
            #pragma unroll
            for (int jj = 0; jj < 2; ++jj) {
                int n = (wv * 2 + jj) * 16 + col;
                float z = fmaxf(acc2[mt][jj][i] + mb2[n], 0.f);
                p += z * mw3[n];
            }
            p += __shfl_xor(p, 1);
            p += __shfl_xor(p, 2);
            p += __shfl_xor(p, 4);
            p += __shfl_xor(p, 8);
            if (col == 0) sh_part[wv][mt * 16 + quad * 4 + i] = p;
        }
    }
    __syncthreads();
    if (t < 32)
        out[b0 + t] = sh_part[0][t] + sh_part[1][t] + sh_part[2][t] + sh_part[3][t] + mb3[0];
}

extern "C" void kernel_launch(void* const* d_in, const int* in_sizes, int n_in,
                              void* d_out, int out_size, void* d_ws, size_t ws_size,
                              hipStream_t stream) {
    const int*   cid = (const int*)d_in[0];
    const int*   cg  = (const int*)d_in[1];
    const int*   cc  = (const int*)d_in[2];
    const int*   hg  = (const int*)d_in[3];
    const int*   hc  = (const int*)d_in[4];
    const float* user_table = (const float*)d_in[5];
    const float* item_table = (const float*)d_in[6];
    const float* cat_table  = (const float*)d_in[7];
    const float* aw1 = (const float*)d_in[8];
    const float* ab1 = (const float*)d_in[9];
    const float* aw2 = (const float*)d_in[10];
    const float* mw1 = (const float*)d_in[12];
    const float* mb1 = (const float*)d_in[13];
    const float* mw2 = (const float*)d_in[14];
    const float* mb2 = (const float*)d_in[15];
    const float* mw3 = (const float*)d_in[16];
    const float* mb3 = (const float*)d_in[17];
    float* out = (float*)d_out;

    const int B = in_sizes[0];                    // 16384
    const int itemN = in_sizes[6];                // NI*32
    const int catN  = in_sizes[7];                // NC*32
    float* ws = (float*)d_ws;
    float* Awt = ws;
    unsigned short* Bmfb = (unsigned short*)(ws + 5120);
    unsigned short* W4fb = (unsigned short*)(ws + 7680);
    unsigned short* W1f  = (unsigned short*)(ws + 10240);
    unsigned short* W2f  = (unsigned short*)(ws + 30720);
    unsigned short* itemb = (unsigned short*)(ws + 47104);
    unsigned short* catb  = itemb + itemN;
    float* combined = ws + 47104 + (itemN + catN + 1) / 2;

    int n8 = (itemN + 7) / 8;
    int prep_grid = (n8 + 255) / 256;             // also covers weight ranges (<=40960)
    if (prep_grid < 160) prep_grid = 160;
    prep_kernel<<<prep_grid, 256, 0, stream>>>(aw1, mw1, mw2, item_table, cat_table,
                                               itemN, catN, Awt, Bmfb, W4fb, W1f, W2f,
                                               itemb, catb);
    attn_kernel<<<B / 2, 256, 0, stream>>>(cid, cg, cc, hg, hc,
                                           user_table, item_table, cat_table,
                                           ab1, aw2, Awt, Bmfb, W4fb, itemb, catb, combined);
    mlp_kernel<<<B / 32, 256, 0, stream>>>(combined, W1f, W2f,
                                           mb1, mb2, mw3, mb3, out);
}

// Round 6
// 197.581 us; speedup vs baseline: 2.1990x; 1.0056x over previous
//
#include <hip/hip_runtime.h>
#include <math.h>

#define LHIST 50

typedef __attribute__((ext_vector_type(8))) short bf16x8;
typedef __attribute__((ext_vector_type(4))) float f32x4;

__device__ __forceinline__ unsigned short f2bf(float f) {
    union { float f; unsigned u; } v; v.f = f;
    unsigned r = v.u + 0x7fff + ((v.u >> 16) & 1);   // RNE
    return (unsigned short)(r >> 16);
}
__device__ __forceinline__ float bf2f(unsigned short h) {
    union { unsigned u; float f; } v; v.u = ((unsigned)h) << 16;
    return v.f;
}

// ws float offsets:
//  Awt    [80][64] fp32                   @ 0         (5120)
//  Bmfb   frag bf16 [nt5][ks2][lane][8]   @ 5120      (2560 f)
//  W4fb   frag bf16 [nt5][ks2][lane][8]   @ 7680      (2560 f)
//  W1f    frag bf16 [nt16][ks5][lane][8]  @ 10240     (20480 f)
//  W2f    frag bf16 [nt8][ks8][lane][8]   @ 30720     (16384 f)
//  itemb  bf16 [NI*32]                    @ 47104     (NI*16 f)
//  catb   bf16 [NC*32]                    @ 47104+NI*16
//  cfrag  bf16 [B/16][ks5][lane][8]       after catb  (combined, MFMA A-frag layout)

__global__ void prep_kernel(const float* __restrict__ aw1,
                            const float* __restrict__ mw1,
                            const float* __restrict__ mw2,
                            const float* __restrict__ item_table,
                            const float* __restrict__ cat_table,
                            int itemN, int catN,
                            float* __restrict__ Awt,
                            unsigned short* __restrict__ Bmfb,
                            unsigned short* __restrict__ W4fb,
                            unsigned short* __restrict__ W1f,
                            unsigned short* __restrict__ W2f,
                            unsigned short* __restrict__ itemb,
                            unsigned short* __restrict__ catb) {
    int i = blockIdx.x * 256 + threadIdx.x;
    int i8 = i * 8;
    if (i8 + 7 < itemN) {
        float4 a = *(const float4*)&item_table[i8];
        float4 b = *(const float4*)&item_table[i8 + 4];
        ushort4 lo, hi;
        lo.x = f2bf(a.x); lo.y = f2bf(a.y); lo.z = f2bf(a.z); lo.w = f2bf(a.w);
        hi.x = f2bf(b.x); hi.y = f2bf(b.y); hi.z = f2bf(b.z); hi.w = f2bf(b.w);
        *(ushort4*)&itemb[i8] = lo;
        *(ushort4*)&itemb[i8 + 4] = hi;
    }
    if (i8 + 7 < catN) {
        float4 a = *(const float4*)&cat_table[i8];
        float4 b = *(const float4*)&cat_table[i8 + 4];
        ushort4 lo, hi;
        lo.x = f2bf(a.x); lo.y = f2bf(a.y); lo.z = f2bf(a.z); lo.w = f2bf(a.w);
        hi.x = f2bf(b.x); hi.y = f2bf(b.y); hi.z = f2bf(b.z); hi.w = f2bf(b.w);
        *(ushort4*)&catb[i8] = lo;
        *(ushort4*)&catb[i8 + 4] = hi;
    }
    if (i < 5120) {
        int j = i >> 6, k = i & 63;
        Awt[i] = aw1[k * 80 + j] + aw1[(128 + k) * 80 + j];     // (W1+W3)^T
        int kk = i / 80, n = i - kk * 80;
        int nt = n >> 4, colw = n & 15, ks = kk >> 5, r = kk & 31, qd = r >> 3, off = r & 7;
        int d = ((nt * 2 + ks) * 64 + qd * 16 + colw) * 8 + off;
        Bmfb[d] = f2bf(aw1[(64 + kk) * 80 + n] - aw1[(128 + kk) * 80 + n]);  // W2-W3
        W4fb[d] = f2bf(aw1[(192 + kk) * 80 + n]);
    }
    if (i < 40960) {
        int kk = i >> 8, n = i & 255;
        int nt = n >> 4, colw = n & 15, ks = kk >> 5, r = kk & 31, qd = r >> 3, off = r & 7;
        W1f[((nt * 5 + ks) * 64 + qd * 16 + colw) * 8 + off] = f2bf(mw1[i]);
    }
    if (i < 32768) {
        int kk = i >> 7, n = i & 127;
        int nt = n >> 4, colw = n & 15, ks = kk >> 5, r = kk & 31, qd = r >> 3, off = r & 7;
        W2f[((nt * 8 + ks) * 64 + qd * 16 + colw) * 8 + off] = f2bf(mw2[i]);
    }
}

__device__ __forceinline__ bf16x8 hq_frag(uint4 v, const float* qp) {
    union { uint4 u; unsigned short s[8]; } in; in.u = v;
    bf16x8 r;
    #pragma unroll
    for (int j = 0; j < 8; ++j) r[j] = (short)f2bf(bf2f(in.s[j]) * qp[j]);
    return r;
}

// ---------- attention: 4 batches / 256-thread block (1 batch per wave), K=128 ----------
__global__ void __launch_bounds__(256, 4) attn_kernel(
    const int* __restrict__ cid, const int* __restrict__ cg,
    const int* __restrict__ cc,  const int* __restrict__ hg,
    const int* __restrict__ hc,
    const float* __restrict__ user_table, const float* __restrict__ item_table,
    const float* __restrict__ cat_table,
    const float* __restrict__ ab1, const float* __restrict__ aw2,
    const float* __restrict__ Awt, const unsigned short* __restrict__ Bmfb,
    const unsigned short* __restrict__ W4fb,
    const unsigned short* __restrict__ itemb, const unsigned short* __restrict__ catb,
    unsigned short* __restrict__ cfrag)
{
    __shared__ __align__(16) unsigned short sh_B[20 * 64 * 8];   // [nt5][ks4][lane][8]
    __shared__ __align__(16) float sh_q[4][64];
    __shared__ float sh_bias[4][80];
    __shared__ float sh_sc[4][64];
    __shared__ float sh_aw2[80];

    const int t = threadIdx.x;
    const int b0 = blockIdx.x * 4;
    const int wv = t >> 6;
    const int lane = t & 63;
    const int quad = lane >> 4;
    const int col = lane & 15;

    // ---- P0: B-frags (batch-independent!), q, aw2 ----
    for (int i = t; i < 1280; i += 256) {
        int lane8 = i & 63;
        int ksnt = i >> 6;              // 0..19: nt*4+ks
        int nt = ksnt >> 2, ks = ksnt & 3;
        const unsigned short* src = (ks < 2)
            ? &Bmfb[((nt * 2 + ks) * 64 + lane8) * 8]
            : &W4fb[((nt * 2 + (ks - 2)) * 64 + lane8) * 8];
        *(uint4*)&sh_B[i * 8] = *(const uint4*)src;
    }
    {
        int qbi = wv;
        int b = b0 + qbi;
        float v = (lane < 32) ? item_table[(size_t)cg[b] * 32 + lane]
                              : cat_table[(size_t)cc[b] * 32 + (lane - 32)];
        sh_q[qbi][lane] = v;
    }
    if (t < 80) sh_aw2[t] = aw2[t];
    __syncthreads();

    const int b = b0 + wv;

    // ---- per-wave: history indices + issue pair-0 gathers ----
    int il[4], ic[4];
    #pragma unroll
    for (int mt = 0; mt < 4; ++mt) {
        int l = mt * 16 + col;
        int lc = (l < LHIST) ? l : 0;
        il[mt] = hg[b * LHIST + lc];
        ic[mt] = hc[b * LHIST + lc];
    }
    uint4 vi0 = *(const uint4*)&itemb[(size_t)il[0] * 32 + quad * 8];
    uint4 vc0 = *(const uint4*)&catb[(size_t)ic[0] * 32 + quad * 8];
    uint4 vi1 = *(const uint4*)&itemb[(size_t)il[1] * 32 + quad * 8];
    uint4 vc1 = *(const uint4*)&catb[(size_t)ic[1] * 32 + quad * 8];

    // ---- P1: bias[b][j] = ab1[j] + q.(W1+W3)[:,j] (fp32, all threads) ----
    for (int s = t; s < 320; s += 256) {
        int bi = s / 80, j = s - bi * 80;
        float acc = ab1[j];
        const float4* aw = (const float4*)&Awt[j * 64];
        #pragma unroll
        for (int k4 = 0; k4 < 16; ++k4) {
            float4 a = aw[k4];
            float4 q = *(const float4*)&sh_q[bi][k4 * 4];
            acc += a.x * q.x + a.y * q.y + a.z * q.z + a.w * q.w;
        }
        sh_bias[bi][j] = acc;
    }
    __syncthreads();

    // q slices for h*q frags
    float q0[8], q1[8];
    {
        float4 qa = *(const float4*)&sh_q[wv][quad * 8];
        float4 qb = *(const float4*)&sh_q[wv][quad * 8 + 4];
        q0[0]=qa.x; q0[1]=qa.y; q0[2]=qa.z; q0[3]=qa.w; q0[4]=qb.x; q0[5]=qb.y; q0[6]=qb.z; q0[7]=qb.w;
        float4 qc = *(const float4*)&sh_q[wv][32 + quad * 8];
        float4 qdv = *(const float4*)&sh_q[wv][32 + quad * 8 + 4];
        q1[0]=qc.x; q1[1]=qc.y; q1[2]=qc.z; q1[3]=qc.w; q1[4]=qdv.x; q1[5]=qdv.y; q1[6]=qdv.z; q1[7]=qdv.w;
    }
    float bias_v[5], a2_v[5];
    #pragma unroll
    for (int nt = 0; nt < 5; ++nt) {
        bias_v[nt] = sh_bias[wv][nt * 16 + col];
        a2_v[nt]   = sh_aw2[nt * 16 + col];
    }

    // ---- MFMA in two mt-pairs; epilogue per pair -> sh_sc ----
    #pragma unroll
    for (int p = 0; p < 2; ++p) {
        bf16x8 afr[2][4];
        uint4 vi[2], vc[2];
        if (p == 0) { vi[0] = vi0; vc[0] = vc0; vi[1] = vi1; vc[1] = vc1; }
        else {
            vi[0] = *(const uint4*)&itemb[(size_t)il[2] * 32 + quad * 8];
            vc[0] = *(const uint4*)&catb[(size_t)ic[2] * 32 + quad * 8];
            vi[1] = *(const uint4*)&itemb[(size_t)il[3] * 32 + quad * 8];
            vc[1] = *(const uint4*)&catb[(size_t)ic[3] * 32 + quad * 8];
            if (48 + col >= LHIST) { vi[1] = make_uint4(0,0,0,0); vc[1] = make_uint4(0,0,0,0); }
        }
        #pragma unroll
        for (int mi = 0; mi < 2; ++mi) {
            afr[mi][0] = *(bf16x8*)&vi[mi];
            afr[mi][1] = *(bf16x8*)&vc[mi];
            afr[mi][2] = hq_frag(vi[mi], q0);
            afr[mi][3] = hq_frag(vc[mi], q1);
        }
        f32x4 acc[2][5];
        #pragma unroll
        for (int mi = 0; mi < 2; ++mi)
            #pragma unroll
            for (int nt = 0; nt < 5; ++nt) acc[mi][nt] = (f32x4){0.f,0.f,0.f,0.f};
        #pragma unroll
        for (int ks = 0; ks < 4; ++ks) {
            #pragma unroll
            for (int nt = 0; nt < 5; ++nt) {
                bf16x8 bfr = *(const bf16x8*)&sh_B[((nt * 4 + ks) * 64 + lane) * 8];
                acc[0][nt] = __builtin_amdgcn_mfma_f32_16x16x32_bf16(afr[0][ks], bfr, acc[0][nt], 0, 0, 0);
                acc[1][nt] = __builtin_amdgcn_mfma_f32_16x16x32_bf16(afr[1][ks], bfr, acc[1][nt], 0, 0, 0);
            }
        }
        // epilogue: scores
        #pragma unroll
        for (int mi = 0; mi < 2; ++mi) {
            int mt = p * 2 + mi;
            #pragma unroll
            for (int i = 0; i < 4; ++i) {
                float pp = 0.f;
                #pragma unroll
                for (int nt = 0; nt < 5; ++nt) {
                    float u = acc[mi][nt][i] + bias_v[nt];
                    pp += fmaxf(u, 0.f) * a2_v[nt];
                }
                pp += __shfl_xor(pp, 1);
                pp += __shfl_xor(pp, 2);
                pp += __shfl_xor(pp, 4);
                pp += __shfl_xor(pp, 8);
                if (col == 0) sh_sc[wv][mt * 16 + quad * 4 + i] = pp;
            }
        }
    }

    // ---- softmax (wave-local; LDS ops within a wave are ordered) ----
    float sc = -INFINITY;
    if (lane < LHIST) {
        sc = sh_sc[wv][lane];
        if (hg[b * LHIST + lane] == 0) sc = -1e9f;
    }
    float m = sc;
    #pragma unroll
    for (int off = 32; off > 0; off >>= 1) m = fmaxf(m, __shfl_xor(m, off));
    float e = (lane < LHIST) ? __expf(sc - m) : 0.f;
    float ssum = e;
    #pragma unroll
    for (int off = 32; off > 0; off >>= 1) ssum += __shfl_xor(ssum, off);
    float w = e / ssum;    // 0 for lane >= LHIST

    // ---- att: re-gather (L1/L2-hot), lanes split d-chunks ----
    int c = lane & 7, lgrp = lane >> 3;
    int isCat = c >> 2, s4 = c & 3;
    float at[8];
    #pragma unroll
    for (int j = 0; j < 8; ++j) at[j] = 0.f;
    #pragma unroll
    for (int it = 0; it < 7; ++it) {
        int l = it * 8 + lgrp;
        int lc = (l < LHIST) ? l : 0;
        float wl = __shfl(w, l);
        int idx = (isCat ? hc : hg)[b * LHIST + lc];
        uint4 hv = *(const uint4*)&(isCat ? catb : itemb)[(size_t)idx * 32 + s4 * 8];
        union { uint4 u; unsigned short s[8]; } hh; hh.u = hv;
        #pragma unroll
        for (int j = 0; j < 8; ++j) at[j] += wl * bf2f(hh.s[j]);
    }
    #pragma unroll
    for (int off = 8; off < 64; off <<= 1)
        #pragma unroll
        for (int j = 0; j < 8; ++j) at[j] += __shfl_xor(at[j], off);

    // ---- write combined directly in MFMA A-frag layout (bf16) ----
    {
        int g = b >> 4, colm = b & 15;
        unsigned short* base = cfrag + (size_t)g * 2560;
        if (lane < 8) {                       // att chunks: k = 96 + lane*8
            int k0 = 96 + lane * 8;
            int ks = k0 >> 5, qd = (k0 >> 3) & 3;
            ushort4 lo, hi;
            lo.x = f2bf(at[0]); lo.y = f2bf(at[1]); lo.z = f2bf(at[2]); lo.w = f2bf(at[3]);
            hi.x = f2bf(at[4]); hi.y = f2bf(at[5]); hi.z = f2bf(at[6]); hi.w = f2bf(at[7]);
            unsigned short* p = base + ((ks * 64) + qd * 16 + colm) * 8;
            *(ushort4*)p = lo;
            *(ushort4*)(p + 4) = hi;
        } else if (lane < 16) {               // q chunks: k = 32 + (lane-8)*8
            int cq = lane - 8;
            int k0 = 32 + cq * 8;
            int ks = k0 >> 5, qd = (k0 >> 3) & 3;
            float4 qa = *(const float4*)&sh_q[wv][cq * 8];
            float4 qb = *(const float4*)&sh_q[wv][cq * 8 + 4];
            ushort4 lo, hi;
            lo.x = f2bf(qa.x); lo.y = f2bf(qa.y); lo.z = f2bf(qa.z); lo.w = f2bf(qa.w);
            hi.x = f2bf(qb.x); hi.y = f2bf(qb.y); hi.z = f2bf(qb.z); hi.w = f2bf(qb.w);
            unsigned short* p = base + ((ks * 64) + qd * 16 + colm) * 8;
            *(ushort4*)p = lo;
            *(ushort4*)(p + 4) = hi;
        } else if (lane < 20) {               // user chunks: k = (lane-16)*8
            int cu = lane - 16;
            int uidx = cid[b];
            float4 ua = *(const float4*)&user_table[(size_t)uidx * 32 + cu * 8];
            float4 ub = *(const float4*)&user_table[(size_t)uidx * 32 + cu * 8 + 4];
            ushort4 lo, hi;
            lo.x = f2bf(ua.x); lo.y = f2bf(ua.y); lo.z = f2bf(ua.z); lo.w = f2bf(ua.w);
            hi.x = f2bf(ub.x); hi.y = f2bf(ub.y); hi.z = f2bf(ub.z); hi.w = f2bf(ub.w);
            unsigned short* p = base + (cu * 16 + colm) * 8;
            *(ushort4*)p = lo;
            *(ushort4*)(p + 4) = hi;
        }
    }
}

// ---------- MLP: MFMA, 16 batches (1 m-tile) per 256-thread block ----------
__global__ void __launch_bounds__(256, 4) mlp_kernel(
    const unsigned short* __restrict__ cfrag,
    const unsigned short* __restrict__ W1f, const unsigned short* __restrict__ W2f,
    const float* __restrict__ mb1, const float* __restrict__ mb2,
    const float* __restrict__ mw3, const float* __restrict__ mb3,
    float* __restrict__ out)
{
    __shared__ __align__(16) unsigned short shA2[4096];   // [ks8][lane][8]
    __shared__ float sh_part[4][16];

    const int t = threadIdx.x;
    const int g = blockIdx.x;
    const int wv = t >> 6;
    const int lane = t & 63;
    const int quad = lane >> 4;
    const int col = lane & 15;
    const unsigned short* abase = cfrag + (size_t)g * 2560;

    // layer 1: z1[16][256], wave owns n-tiles wv*4..wv*4+3; A straight from global
    f32x4 acc1[4];
    #pragma unroll
    for (int j = 0; j < 4; ++j) acc1[j] = (f32x4){0.f, 0.f, 0.f, 0.f};
    #pragma unroll
    for (int ks = 0; ks < 5; ++ks) {
        bf16x8 a = *(const bf16x8*)&abase[(ks * 64 + lane) * 8];
        #pragma unroll
        for (int j = 0; j < 4; ++j) {
            bf16x8 bw = *(const bf16x8*)&W1f[(((wv * 4 + j) * 5 + ks) * 64 + lane) * 8];
            acc1[j] = __builtin_amdgcn_mfma_f32_16x16x32_bf16(a, bw, acc1[j], 0, 0, 0);
        }
    }
    #pragma unroll
    for (int j = 0; j < 4; ++j) {
        int n = (wv * 4 + j) * 16 + col;
        float bj = mb1[n];
        int ks2 = n >> 5, qd2 = (n >> 3) & 3, off2 = n & 7;
        #pragma unroll
        for (int i = 0; i < 4; ++i) {
            float z = fmaxf(acc1[j][i] + bj, 0.f);
            shA2[(ks2 * 64 + qd2 * 16 + quad * 4 + i) * 8 + off2] = f2bf(z);
        }
    }
    __syncthreads();

    // layer 2: z2[16][128], wave owns n-tiles wv*2, wv*2+1
    f32x4 acc2[2];
    #pragma unroll
    for (int jj = 0; jj < 2; ++jj) acc2[jj] = (f32x4){0.f, 0.f, 0.f, 0.f};
    #pragma unroll
    for (int ks = 0; ks < 8; ++ks) {
        bf16x8 a = *(const bf16x8*)&shA2[(ks * 64 + lane) * 8];
        #pragma unroll
        for (int jj = 0; jj < 2; ++jj) {
            bf16x8 bw = *(const bf16x8*)&W2f[(((wv * 2 + jj) * 8 + ks) * 64 + lane) * 8];
            acc2[jj] = __builtin_amdgcn_mfma_f32_16x16x32_bf16(a, bw, acc2[jj], 0, 0, 0);
        }
    }
    // layer 3
    #pragma unroll
    for (int i = 0; i < 4; ++i) {
        float p = 0.f;
        #pragma unroll
        for (int jj = 0; jj < 2; ++jj) {
            int n = (wv * 2 + jj) * 16 + col;
            float z = fmaxf(acc2[jj][i] + mb2[n], 0.f);
            p += z * mw3[n];
        }
        p += __shfl_xor(p, 1);
        p += __shfl_xor(p, 2);
        p += __shfl_xor(p, 4);
        p += __shfl_xor(p, 8);
        if (col == 0) sh_part[wv][quad * 4 + i] = p;
    }
    __syncthreads();
    if (t < 16)
        out[g * 16 + t] = sh_part[0][t] + sh_part[1][t] + sh_part[2][t] + sh_part[3][t] + mb3[0];
}

extern "C" void kernel_launch(void* const* d_in, const int* in_sizes, int n_in,
                              void* d_out, int out_size, void* d_ws, size_t ws_size,
                              hipStream_t stream) {
    const int*   cid = (const int*)d_in[0];
    const int*   cg  = (const int*)d_in[1];
    const int*   cc  = (const int*)d_in[2];
    const int*   hg  = (const int*)d_in[3];
    const int*   hc  = (const int*)d_in[4];
    const float* user_table = (const float*)d_in[5];
    const float* item_table = (const float*)d_in[6];
    const float* cat_table  = (const float*)d_in[7];
    const float* aw1 = (const float*)d_in[8];
    const float* ab1 = (const float*)d_in[9];
    const float* aw2 = (const float*)d_in[10];
    const float* mw1 = (const float*)d_in[12];
    const float* mb1 = (const float*)d_in[13];
    const float* mw2 = (const float*)d_in[14];
    const float* mb2 = (const float*)d_in[15];
    const float* mw3 = (const float*)d_in[16];
    const float* mb3 = (const float*)d_in[17];
    float* out = (float*)d_out;

    const int B = in_sizes[0];                    // 16384
    const int itemN = in_sizes[6];                // NI*32
    const int catN  = in_sizes[7];                // NC*32
    float* ws = (float*)d_ws;
    float* Awt = ws;
    unsigned short* Bmfb = (unsigned short*)(ws + 5120);
    unsigned short* W4fb = (unsigned short*)(ws + 7680);
    unsigned short* W1f  = (unsigned short*)(ws + 10240);
    unsigned short* W2f  = (unsigned short*)(ws + 30720);
    unsigned short* itemb = (unsigned short*)(ws + 47104);
    unsigned short* catb  = itemb + itemN;
    unsigned short* cfrag = (unsigned short*)(ws + 47104 + (itemN + catN + 1) / 2);

    int n8 = (itemN + 7) / 8;
    int prep_grid = (n8 + 255) / 256;
    if (prep_grid < 160) prep_grid = 160;
    prep_kernel<<<prep_grid, 256, 0, stream>>>(aw1, mw1, mw2, item_table, cat_table,
                                               itemN, catN, Awt, Bmfb, W4fb, W1f, W2f,
                                               itemb, catb);
    attn_kernel<<<B / 4, 256, 0, stream>>>(cid, cg, cc, hg, hc,
                                           user_table, item_table, cat_table,
                                           ab1, aw2, Awt, Bmfb, W4fb, itemb, catb, cfrag);
    mlp_kernel<<<B / 16, 256, 0, stream>>>(cfrag, W1f, W2f,
                                           mb1, mb2, mw3, mb3, out);
}